// Round 1
// baseline (1550.516 us; speedup 1.0000x reference)
//
#include <hip/hip_runtime.h>
#include <hip/hip_bf16.h>

// Problem constants
#define NATOMS 4096     // B*N = 8*512
#define S_ 128
#define DESC_ 2048
#define H_ 256
#define MAXTILES 67     // sum ceil(cnt_t/64) <= 64+3

__device__ __forceinline__ float fast_tanh(float x) {
    // tanh(x) = 1 - 2/(exp(2x)+1); handles +/-inf of exp gracefully
    float e = __expf(2.0f * x);
    return 1.0f - 2.0f / (e + 1.0f);
}

// ---------------------------------------------------------------------------
// Deterministic counting sort of atoms by type + type-pure 64-atom tile list.
// meta[0] = ntiles; meta[1+3i..] = (type, start_pos, count<=64)
// ---------------------------------------------------------------------------
__global__ __launch_bounds__(256) void build_perm_kernel(
    const int* __restrict__ types, int* __restrict__ perm, int* __restrict__ meta)
{
    __shared__ int cnt[256 * 4];
    __shared__ int tstart[5];
    int tid = threadIdx.x;
    int base = tid * 16;
    int c0 = 0, c1 = 0, c2 = 0, c3 = 0;
    for (int i = 0; i < 16; ++i) {
        int t = types[base + i];
        c0 += (t == 0); c1 += (t == 1); c2 += (t == 2); c3 += (t == 3);
    }
    cnt[tid * 4 + 0] = c0; cnt[tid * 4 + 1] = c1;
    cnt[tid * 4 + 2] = c2; cnt[tid * 4 + 3] = c3;
    __syncthreads();
    if (tid == 0) {
        int run = 0;
        for (int t = 0; t < 4; ++t) {
            tstart[t] = run;
            for (int th = 0; th < 256; ++th) {
                int v = cnt[th * 4 + t];
                cnt[th * 4 + t] = run;
                run += v;
            }
        }
        tstart[4] = run;
        int nt = 0;
        for (int t = 0; t < 4; ++t) {
            int cT = tstart[t + 1] - tstart[t];
            for (int off = 0; off < cT; off += 64) {
                meta[1 + nt * 3 + 0] = t;
                meta[1 + nt * 3 + 1] = tstart[t] + off;
                meta[1 + nt * 3 + 2] = (cT - off < 64) ? (cT - off) : 64;
                nt++;
            }
        }
        meta[0] = nt;
    }
    __syncthreads();
    for (int i = 0; i < 16; ++i) {
        int idx = base + i;
        int t = types[idx];
        perm[cnt[tid * 4 + t]++] = idx;   // thread-private LDS slot: deterministic
    }
}

// ---------------------------------------------------------------------------
// Filter net + descriptor per atom. One 256-thread block per sorted position.
// Writes D[p][2048] (sorted order) to ws.
// LDS strides padded (36/68/132) to avoid 32-way bank conflicts.
// ---------------------------------------------------------------------------
__global__ __launch_bounds__(256) void filter_kernel(
    const float* __restrict__ sym, const int* __restrict__ types,
    const int* __restrict__ perm,
    const float* __restrict__ Wf0, const float* __restrict__ bf0,
    const float* __restrict__ Wf1, const float* __restrict__ bf1,
    const float* __restrict__ Wf2, const float* __restrict__ bf2,
    float* __restrict__ D)
{
    __shared__ float Rl[S_ * 4];        // 2 KB   [s][d]
    __shared__ float G0[S_ * 36];       // 18 KB  [s][f] pad 36
    __shared__ float G1[S_ * 68];       // 34 KB  [s][g] pad 68
    __shared__ float G2[S_ * 132];      // 66 KB  [s][m] pad 132
    __shared__ float RGl[4 * 128];      // 2 KB   [d][m]

    int p = blockIdx.x;
    int tid = threadIdx.x;
    int atom = perm[p];
    int t = __builtin_amdgcn_readfirstlane(types[atom]);

    // Load R (128 x 4 floats, contiguous)
    const float2* src = reinterpret_cast<const float2*>(sym + (size_t)atom * 512);
    reinterpret_cast<float2*>(Rl)[tid] = src[tid];
    __syncthreads();

    // L0: G0[s][f] = tanh(R[s][0]*Wf0[t][f] + bf0[t][f])   (thread: s=tid>>1, half row)
    {
        int s = tid >> 1;
        int f0 = (tid & 1) * 16;
        float sv = Rl[s * 4 + 0];
        #pragma unroll
        for (int q = 0; q < 16; ++q) {
            int f = f0 + q;
            G0[s * 36 + f] = fast_tanh(sv * Wf0[t * 32 + f] + bf0[t * 32 + f]);
        }
    }
    __syncthreads();

    // L1: G1[s][g] = tanh(sum_f G0[s][f] * Wf1[t][g][f] + bf1)   K=32
    {
        int s = tid >> 1;
        int gbase = (tid & 1) * 32;
        float4 g0r[8];
        const float4* g0p = reinterpret_cast<const float4*>(&G0[s * 36]);
        #pragma unroll
        for (int q = 0; q < 8; ++q) g0r[q] = g0p[q];
        for (int g = 0; g < 32; ++g) {
            int gg = gbase + g;
            float acc = bf1[t * 64 + gg];
            const float4* wp = reinterpret_cast<const float4*>(Wf1 + ((size_t)t * 64 + gg) * 32);
            #pragma unroll
            for (int q = 0; q < 8; ++q) {
                float4 w = wp[q];
                acc += w.x * g0r[q].x + w.y * g0r[q].y + w.z * g0r[q].z + w.w * g0r[q].w;
            }
            G1[s * 68 + gg] = fast_tanh(acc);
        }
    }
    __syncthreads();

    // L2: G2[s][m] = tanh(sum_g G1[s][g] * Wf2[t][m][g] + bf2)   K=64
    {
        int s = tid >> 1;
        int mbase = (tid & 1) * 64;
        float4 g1r[16];
        const float4* g1p = reinterpret_cast<const float4*>(&G1[s * 68]);
        #pragma unroll
        for (int q = 0; q < 16; ++q) g1r[q] = g1p[q];
        for (int m = 0; m < 64; ++m) {
            int mm = mbase + m;
            float acc = bf2[t * 128 + mm];
            const float4* wp = reinterpret_cast<const float4*>(Wf2 + ((size_t)t * 128 + mm) * 64);
            #pragma unroll
            for (int q = 0; q < 16; ++q) {
                float4 w = wp[q];
                acc += w.x * g1r[q].x + w.y * g1r[q].y + w.z * g1r[q].z + w.w * g1r[q].w;
            }
            G2[s * 132 + mm] = fast_tanh(acc);
        }
    }
    __syncthreads();

    // RG[d][m] = sum_s R[s][d] * G2[s][m]   (wave d = tid>>6; lanes cover m pairs)
    {
        int d = tid >> 6;
        int m0 = (tid & 63) * 2;
        float a0 = 0.f, a1 = 0.f;
        for (int s = 0; s < 128; ++s) {
            float r = Rl[s * 4 + d];
            float2 g = *reinterpret_cast<const float2*>(&G2[s * 132 + m0]);
            a0 += r * g.x;
            a1 += r * g.y;
        }
        RGl[d * 128 + m0] = a0;
        RGl[d * 128 + m0 + 1] = a1;
    }
    __syncthreads();

    // D[m*16+a] = sum_d RG[d][m] * RG[d][a],  a < 16
    {
        int m = tid >> 1;
        int ab = (tid & 1) * 8;
        float rm0 = RGl[0 * 128 + m], rm1 = RGl[1 * 128 + m];
        float rm2 = RGl[2 * 128 + m], rm3 = RGl[3 * 128 + m];
        float outv[8];
        #pragma unroll
        for (int q = 0; q < 8; ++q) {
            int a = ab + q;
            outv[q] = rm0 * RGl[0 * 128 + a] + rm1 * RGl[1 * 128 + a]
                    + rm2 * RGl[2 * 128 + a] + rm3 * RGl[3 * 128 + a];
        }
        float4* dst = reinterpret_cast<float4*>(D + (size_t)p * DESC_ + m * 16 + ab);
        dst[0] = make_float4(outv[0], outv[1], outv[2], outv[3]);
        dst[1] = make_float4(outv[4], outv[5], outv[6], outv[7]);
    }
}

// ---------------------------------------------------------------------------
// One fitting layer: out[p][h] = tanh(sum_k in[p][k]*W[t][h][k] + bias[t][h])
// Block = (tile of <=64 type-pure atoms) x (64-h quarter). 4 waves, wave = 16 h.
// K-chunked (128) LDS staging of both operands; weights wave-uniform -> broadcast.
// ---------------------------------------------------------------------------
__global__ __launch_bounds__(256) void fit_kernel(
    const float* __restrict__ in,    // [4096][K]
    const float* __restrict__ W,     // [4][256][K]
    const float* __restrict__ bias,  // [4][256]
    float* __restrict__ out,         // [4096][256]
    int K,
    const int* __restrict__ meta)
{
    __shared__ float ldsD[128][64];  // [kk][atom]
    __shared__ float ldsW[128][64];  // [kk][h - hbB]

    int ntiles = meta[0];
    int tile = blockIdx.x >> 2;
    if (tile >= ntiles) return;
    int hq  = blockIdx.x & 3;
    int t   = __builtin_amdgcn_readfirstlane(meta[1 + tile * 3 + 0]);
    int p0  = meta[1 + tile * 3 + 1];
    int cnt = meta[1 + tile * 3 + 2];

    int tid = threadIdx.x;
    int a   = tid & 63;
    int wv  = tid >> 6;
    int hbB = hq * 64;
    int hbW = hbB + wv * 16;

    float acc[16];
    #pragma unroll
    for (int j = 0; j < 16; ++j) acc[j] = 0.f;

    int arow = p0 + a; if (arow > NATOMS - 1) arow = NATOMS - 1;
    const float* inrow = in + (size_t)arow * K;
    int hi  = tid >> 2;                 // 0..63 staging h
    int ksS = (tid & 3) * 32;           // staging k base
    const float* wrow = W + ((size_t)t * 256 + hbB + hi) * K;

    for (int k0 = 0; k0 < K; k0 += 128) {
        { // stage input chunk (transpose to [kk][a])
            const float4* s4 = reinterpret_cast<const float4*>(inrow + k0 + wv * 32);
            #pragma unroll
            for (int q4 = 0; q4 < 8; ++q4) {
                float4 v = s4[q4];
                int kk = wv * 32 + q4 * 4;
                ldsD[kk + 0][a] = v.x;
                ldsD[kk + 1][a] = v.y;
                ldsD[kk + 2][a] = v.z;
                ldsD[kk + 3][a] = v.w;
            }
        }
        { // stage weight chunk (transpose to [kk][h])
            const float4* s4 = reinterpret_cast<const float4*>(wrow + k0 + ksS);
            #pragma unroll
            for (int q4 = 0; q4 < 8; ++q4) {
                float4 v = s4[q4];
                int kk = ksS + q4 * 4;
                ldsW[kk + 0][hi] = v.x;
                ldsW[kk + 1][hi] = v.y;
                ldsW[kk + 2][hi] = v.z;
                ldsW[kk + 3][hi] = v.w;
            }
        }
        __syncthreads();
        #pragma unroll 4
        for (int kk = 0; kk < 128; ++kk) {
            float d = ldsD[kk][a];
            const float4* w4 = reinterpret_cast<const float4*>(&ldsW[kk][wv * 16]);
            #pragma unroll
            for (int j4 = 0; j4 < 4; ++j4) {
                float4 w = w4[j4];
                acc[j4 * 4 + 0] = fmaf(w.x, d, acc[j4 * 4 + 0]);
                acc[j4 * 4 + 1] = fmaf(w.y, d, acc[j4 * 4 + 1]);
                acc[j4 * 4 + 2] = fmaf(w.z, d, acc[j4 * 4 + 2]);
                acc[j4 * 4 + 3] = fmaf(w.w, d, acc[j4 * 4 + 3]);
            }
        }
        __syncthreads();
    }

    if (a < cnt) {
        float o[16];
        #pragma unroll
        for (int j = 0; j < 16; ++j)
            o[j] = fast_tanh(acc[j] + bias[t * 256 + hbW + j]);
        float4* dst = reinterpret_cast<float4*>(out + (size_t)(p0 + a) * 256 + hbW);
        dst[0] = make_float4(o[0], o[1], o[2], o[3]);
        dst[1] = make_float4(o[4], o[5], o[6], o[7]);
        dst[2] = make_float4(o[8], o[9], o[10], o[11]);
        dst[3] = make_float4(o[12], o[13], o[14], o[15]);
    }
}

// ---------------------------------------------------------------------------
// E_atom = h2 . Wo[t] + bo[t]; accumulate into out[b]. One wave per atom.
// ---------------------------------------------------------------------------
__global__ __launch_bounds__(256) void final_kernel(
    const float* __restrict__ h2, const int* __restrict__ perm,
    const int* __restrict__ types,
    const float* __restrict__ Wo, const float* __restrict__ bo,
    float* __restrict__ out)
{
    int tid = threadIdx.x;
    int wv = tid >> 6;
    int lane = tid & 63;
    int p = blockIdx.x * 4 + wv;
    int atom = perm[p];
    int t = types[atom];
    const float* hrow = h2 + (size_t)p * 256;
    float e = 0.f;
    #pragma unroll
    for (int r = 0; r < 4; ++r) {
        int h = r * 64 + lane;
        e += hrow[h] * Wo[t * 256 + h];
    }
    #pragma unroll
    for (int off = 32; off > 0; off >>= 1)
        e += __shfl_xor(e, off, 64);
    if (lane == 0) atomicAdd(&out[atom >> 9], e + bo[t]);
}

// ---------------------------------------------------------------------------
extern "C" void kernel_launch(void* const* d_in, const int* in_sizes, int n_in,
                              void* d_out, int out_size, void* d_ws, size_t ws_size,
                              hipStream_t stream) {
    const float* sym = (const float*)d_in[0];
    const int*   types = (const int*)d_in[1];
    const float* Wf0 = (const float*)d_in[2];
    const float* bf0 = (const float*)d_in[3];
    const float* Wf1 = (const float*)d_in[4];
    const float* bf1 = (const float*)d_in[5];
    const float* Wf2 = (const float*)d_in[6];
    const float* bf2 = (const float*)d_in[7];
    const float* Wt0 = (const float*)d_in[8];
    const float* bt0 = (const float*)d_in[9];
    const float* Wt1 = (const float*)d_in[10];
    const float* bt1 = (const float*)d_in[11];
    const float* Wt2 = (const float*)d_in[12];
    const float* bt2 = (const float*)d_in[13];
    const float* Wo  = (const float*)d_in[14];
    const float* bo  = (const float*)d_in[15];
    float* out = (float*)d_out;

    char* ws = (char*)d_ws;
    int*   meta = (int*)ws;                                     // 1 KB
    int*   perm = (int*)(ws + 1024);                            // 16 KB
    float* Dbuf = (float*)(ws + 32768);                         // 32 MB
    float* h0   = (float*)(ws + 32768 + (size_t)NATOMS * DESC_ * 4);
    float* h1   = h0 + (size_t)NATOMS * 256;
    float* h2   = h1 + (size_t)NATOMS * 256;

    hipMemsetAsync(d_out, 0, out_size * sizeof(float), stream);
    build_perm_kernel<<<1, 256, 0, stream>>>(types, perm, meta);
    filter_kernel<<<NATOMS, 256, 0, stream>>>(sym, types, perm,
                                              Wf0, bf0, Wf1, bf1, Wf2, bf2, Dbuf);
    fit_kernel<<<MAXTILES * 4, 256, 0, stream>>>(Dbuf, Wt0, bt0, h0, 2048, meta);
    fit_kernel<<<MAXTILES * 4, 256, 0, stream>>>(h0,   Wt1, bt1, h1, 256,  meta);
    fit_kernel<<<MAXTILES * 4, 256, 0, stream>>>(h1,   Wt2, bt2, h2, 256,  meta);
    final_kernel<<<NATOMS / 4, 256, 0, stream>>>(h2, perm, types, Wo, bo, out);
}

// Round 3
// 417.356 us; speedup vs baseline: 3.7151x; 3.7151x over previous
//
#include <hip/hip_runtime.h>
#include <hip/hip_bf16.h>

// Problem constants
#define NATOMS 4096     // B*N = 8*512
#define S_ 128
#define DESC_ 2048
#define H_ 256
#define MAXTILES 67     // sum ceil(cnt_t/64) <= 64+3

typedef short short8 __attribute__((ext_vector_type(8)));
typedef float f32x4 __attribute__((ext_vector_type(4)));
typedef unsigned short u16x8 __attribute__((ext_vector_type(8)));

__device__ __forceinline__ float fast_tanh(float x) {
    // tanh(x) = 1 - 2/(exp(2x)+1); handles +/-inf of exp gracefully
    float e = __expf(2.0f * x);
    return 1.0f - 2.0f * __frcp_rn(e + 1.0f);
}

__device__ __forceinline__ unsigned short f2bf(float f) {
    union { float f; unsigned int u; } v; v.f = f;
    unsigned int r = v.u + 0x7fffu + ((v.u >> 16) & 1u);
    return (unsigned short)(r >> 16);
}
__device__ __forceinline__ float bf2f(unsigned short h) {
    union { unsigned int u; float f; } v; v.u = ((unsigned int)h) << 16;
    return v.f;
}
// split x into hi+lo bf16 pair (x ~= hi + lo to ~16 mantissa bits)
__device__ __forceinline__ void f2bf_split(float x, unsigned short& hi, unsigned short& lo) {
    hi = f2bf(x);
    lo = f2bf(x - bf2f(hi));
}

// ---------------------------------------------------------------------------
// Deterministic counting sort of atoms by type + type-pure 64-atom tile list.
// meta[0] = ntiles; meta[1+3i..] = (type, start_pos, count<=64)
// ---------------------------------------------------------------------------
__global__ __launch_bounds__(256) void build_perm_kernel(
    const int* __restrict__ types, int* __restrict__ perm, int* __restrict__ meta)
{
    __shared__ int cnt[256 * 4];
    __shared__ int tstart[5];
    int tid = threadIdx.x;
    int base = tid * 16;
    int c0 = 0, c1 = 0, c2 = 0, c3 = 0;
    for (int i = 0; i < 16; ++i) {
        int t = types[base + i];
        c0 += (t == 0); c1 += (t == 1); c2 += (t == 2); c3 += (t == 3);
    }
    cnt[tid * 4 + 0] = c0; cnt[tid * 4 + 1] = c1;
    cnt[tid * 4 + 2] = c2; cnt[tid * 4 + 3] = c3;
    __syncthreads();
    if (tid == 0) {
        int run = 0;
        for (int t = 0; t < 4; ++t) {
            tstart[t] = run;
            for (int th = 0; th < 256; ++th) {
                int v = cnt[th * 4 + t];
                cnt[th * 4 + t] = run;
                run += v;
            }
        }
        tstart[4] = run;
        int nt = 0;
        for (int t = 0; t < 4; ++t) {
            int cT = tstart[t + 1] - tstart[t];
            for (int off = 0; off < cT; off += 64) {
                meta[1 + nt * 3 + 0] = t;
                meta[1 + nt * 3 + 1] = tstart[t] + off;
                meta[1 + nt * 3 + 2] = (cT - off < 64) ? (cT - off) : 64;
                nt++;
            }
        }
        meta[0] = nt;
    }
    __syncthreads();
    for (int i = 0; i < 16; ++i) {
        int idx = base + i;
        int t = types[idx];
        perm[cnt[tid * 4 + t]++] = idx;   // thread-private LDS slot: deterministic
    }
}

// ---------------------------------------------------------------------------
// Filter net + descriptor per atom, split-bf16 (hi/lo) MFMA version.
// One 256-thread block (4 waves) per sorted atom position.
// Every MFMA operand is a hi+lo bf16 pair; products Ah*Bh + Ah*Bl + Al*Bh
// accumulate in fp32 -> ~fp32 end-to-end accuracy.
// LDS layout (byte offsets, 77824 total -> 2 blocks/CU):
//   Rl  [128][4]  f32  @ 0
//   G1h [128][72] bf16 @ 2048     G1l @ 20480
//   region A (reused):
//     G0h [128][40] @ 38912      G0l @ 49152
//     W1h [64][40]  @ 59392      W1l @ 64512
//     W2h [128][72] @ 38912      W2l @ 57344   -- after L1
//   RGl [4][128] f32  @ 75776
// ---------------------------------------------------------------------------
__global__ __launch_bounds__(256) void filter_kernel(
    const float* __restrict__ sym, const int* __restrict__ types,
    const int* __restrict__ perm,
    const float* __restrict__ Wf0, const float* __restrict__ bf0,
    const float* __restrict__ Wf1, const float* __restrict__ bf1,
    const float* __restrict__ Wf2, const float* __restrict__ bf2,
    float* __restrict__ D)
{
    __shared__ char lds[77824] __attribute__((aligned(16)));
    float*  Rl  = (float*)lds;                             // [128][4]
    unsigned short* G1h = (unsigned short*)(lds + 2048);   // [128][72]
    unsigned short* G1l = (unsigned short*)(lds + 20480);  // [128][72]
    unsigned short* G0h = (unsigned short*)(lds + 38912);  // [128][40]
    unsigned short* G0l = (unsigned short*)(lds + 49152);  // [128][40]
    unsigned short* W1h = (unsigned short*)(lds + 59392);  // [64][40]
    unsigned short* W1l = (unsigned short*)(lds + 64512);  // [64][40]
    unsigned short* W2h = (unsigned short*)(lds + 38912);  // [128][72]
    unsigned short* W2l = (unsigned short*)(lds + 57344);  // [128][72]
    float*  RGl = (float*)(lds + 75776);                   // [4][128]

    int p = blockIdx.x;
    int tid = threadIdx.x;
    int atom = perm[p];
    int t = __builtin_amdgcn_readfirstlane(types[atom]);
    int lane = tid & 63;
    int wv   = tid >> 6;
    int kg   = lane >> 4;     // k-group / row-group
    int l15  = lane & 15;

    // ---- Phase 0: load R; convert W1 -> hi/lo bf16 LDS --------------------
    ((float2*)Rl)[tid] = ((const float2*)(sym + (size_t)atom * 512))[tid];
    {
        int e = tid * 8;                       // 2048 elems, 8 per thread
        const float4* s4 = (const float4*)(Wf1 + (size_t)t * 2048 + e);
        float4 v0 = s4[0], v1 = s4[1];
        float vv[8] = {v0.x, v0.y, v0.z, v0.w, v1.x, v1.y, v1.z, v1.w};
        u16x8 oh, ol;
        #pragma unroll
        for (int q = 0; q < 8; ++q) { unsigned short h, l; f2bf_split(vv[q], h, l); oh[q] = h; ol[q] = l; }
        int idx = (e >> 5) * 40 + (e & 31);
        *(u16x8*)&W1h[idx] = oh;
        *(u16x8*)&W1l[idx] = ol;
    }
    __syncthreads();

    // ---- Phase 1: L0 -> G0 hi/lo -----------------------------------------
    {
        int s = tid >> 1;
        int f0 = (tid & 1) * 16;
        float sv = Rl[s * 4 + 0];
        u16x8 oh0, ol0, oh1, ol1;
        #pragma unroll
        for (int q = 0; q < 8; ++q) {
            unsigned short h, l;
            f2bf_split(fast_tanh(sv * Wf0[t * 32 + f0 + q] + bf0[t * 32 + f0 + q]), h, l);
            oh0[q] = h; ol0[q] = l;
        }
        #pragma unroll
        for (int q = 0; q < 8; ++q) {
            unsigned short h, l;
            f2bf_split(fast_tanh(sv * Wf0[t * 32 + f0 + 8 + q] + bf0[t * 32 + f0 + 8 + q]), h, l);
            oh1[q] = h; ol1[q] = l;
        }
        *(u16x8*)&G0h[s * 40 + f0]     = oh0;
        *(u16x8*)&G0l[s * 40 + f0]     = ol0;
        *(u16x8*)&G0h[s * 40 + f0 + 8] = oh1;
        *(u16x8*)&G0l[s * 40 + f0 + 8] = ol1;
    }
    __syncthreads();

    // ---- Phase 2: L1 (K=32) -> G1 hi/lo ----------------------------------
    {
        short8 b1h[4], b1l[4];
        float  bias1[4];
        #pragma unroll
        for (int nt = 0; nt < 4; ++nt) {
            int idx = (nt * 16 + l15) * 40 + kg * 8;
            b1h[nt] = *(const short8*)&W1h[idx];
            b1l[nt] = *(const short8*)&W1l[idx];
            bias1[nt] = bf1[t * 64 + nt * 16 + l15];
        }
        #pragma unroll
        for (int mi = 0; mi < 2; ++mi) {
            int mt = wv * 2 + mi;
            int aidx = (mt * 16 + l15) * 40 + kg * 8;
            short8 ah = *(const short8*)&G0h[aidx];
            short8 al = *(const short8*)&G0l[aidx];
            #pragma unroll
            for (int nt = 0; nt < 4; ++nt) {
                f32x4 acc = {0.f, 0.f, 0.f, 0.f};
                acc = __builtin_amdgcn_mfma_f32_16x16x32_bf16(ah, b1h[nt], acc, 0, 0, 0);
                acc = __builtin_amdgcn_mfma_f32_16x16x32_bf16(ah, b1l[nt], acc, 0, 0, 0);
                acc = __builtin_amdgcn_mfma_f32_16x16x32_bf16(al, b1h[nt], acc, 0, 0, 0);
                int rowb = mt * 16 + kg * 4;
                #pragma unroll
                for (int r = 0; r < 4; ++r) {
                    unsigned short h, l;
                    f2bf_split(fast_tanh(acc[r] + bias1[nt]), h, l);
                    G1h[(rowb + r) * 72 + nt * 16 + l15] = h;
                    G1l[(rowb + r) * 72 + nt * 16 + l15] = l;
                }
            }
        }
    }
    __syncthreads();

    // ---- Phase 3: convert W2 -> hi/lo bf16 LDS (overwrites G0/W1) --------
    {
        const float* Wsrc = Wf2 + (size_t)t * 8192;
        #pragma unroll
        for (int q = 0; q < 4; ++q) {
            int e = tid * 32 + q * 8;
            float4 v0 = *(const float4*)(Wsrc + e);
            float4 v1 = *(const float4*)(Wsrc + e + 4);
            float vv[8] = {v0.x, v0.y, v0.z, v0.w, v1.x, v1.y, v1.z, v1.w};
            u16x8 oh, ol;
            #pragma unroll
            for (int j = 0; j < 8; ++j) { unsigned short h, l; f2bf_split(vv[j], h, l); oh[j] = h; ol[j] = l; }
            int idx = (e >> 6) * 72 + (e & 63);
            *(u16x8*)&W2h[idx] = oh;
            *(u16x8*)&W2l[idx] = ol;
        }
    }
    __syncthreads();

    // ---- Phase 4: L2 (K=64) fused with RG contraction --------------------
    // wave wv owns G2 columns [wv*32, wv*32+32)
    {
        short8 b2h[2][2], b2l[2][2];   // [ntl][ks]
        float  bias2[2];
        #pragma unroll
        for (int ntl = 0; ntl < 2; ++ntl) {
            int nt = wv * 2 + ntl;
            bias2[ntl] = bf2[t * 128 + nt * 16 + l15];
            #pragma unroll
            for (int ks = 0; ks < 2; ++ks) {
                int idx = (nt * 16 + l15) * 72 + ks * 32 + kg * 8;
                b2h[ntl][ks] = *(const short8*)&W2h[idx];
                b2l[ntl][ks] = *(const short8*)&W2l[idx];
            }
        }
        float rg[4][2];
        #pragma unroll
        for (int d = 0; d < 4; ++d) { rg[d][0] = 0.f; rg[d][1] = 0.f; }

        #pragma unroll 2
        for (int mt = 0; mt < 8; ++mt) {
            int i0 = (mt * 16 + l15) * 72 + kg * 8;
            short8 a0h = *(const short8*)&G1h[i0];
            short8 a0l = *(const short8*)&G1l[i0];
            short8 a1h = *(const short8*)&G1h[i0 + 32];
            short8 a1l = *(const short8*)&G1l[i0 + 32];
            f32x4 acc0 = {0.f,0.f,0.f,0.f}, acc1 = {0.f,0.f,0.f,0.f};
            acc0 = __builtin_amdgcn_mfma_f32_16x16x32_bf16(a0h, b2h[0][0], acc0, 0,0,0);
            acc0 = __builtin_amdgcn_mfma_f32_16x16x32_bf16(a0h, b2l[0][0], acc0, 0,0,0);
            acc0 = __builtin_amdgcn_mfma_f32_16x16x32_bf16(a0l, b2h[0][0], acc0, 0,0,0);
            acc0 = __builtin_amdgcn_mfma_f32_16x16x32_bf16(a1h, b2h[0][1], acc0, 0,0,0);
            acc0 = __builtin_amdgcn_mfma_f32_16x16x32_bf16(a1h, b2l[0][1], acc0, 0,0,0);
            acc0 = __builtin_amdgcn_mfma_f32_16x16x32_bf16(a1l, b2h[0][1], acc0, 0,0,0);
            acc1 = __builtin_amdgcn_mfma_f32_16x16x32_bf16(a0h, b2h[1][0], acc1, 0,0,0);
            acc1 = __builtin_amdgcn_mfma_f32_16x16x32_bf16(a0h, b2l[1][0], acc1, 0,0,0);
            acc1 = __builtin_amdgcn_mfma_f32_16x16x32_bf16(a0l, b2h[1][0], acc1, 0,0,0);
            acc1 = __builtin_amdgcn_mfma_f32_16x16x32_bf16(a1h, b2h[1][1], acc1, 0,0,0);
            acc1 = __builtin_amdgcn_mfma_f32_16x16x32_bf16(a1h, b2l[1][1], acc1, 0,0,0);
            acc1 = __builtin_amdgcn_mfma_f32_16x16x32_bf16(a1l, b2h[1][1], acc1, 0,0,0);
            int rowb = mt * 16 + kg * 4;
            #pragma unroll
            for (int r = 0; r < 4; ++r) {
                float4 R4 = *(const float4*)&Rl[(rowb + r) * 4];
                float g0 = fast_tanh(acc0[r] + bias2[0]);
                float g1 = fast_tanh(acc1[r] + bias2[1]);
                rg[0][0] += R4.x * g0; rg[1][0] += R4.y * g0;
                rg[2][0] += R4.z * g0; rg[3][0] += R4.w * g0;
                rg[0][1] += R4.x * g1; rg[1][1] += R4.y * g1;
                rg[2][1] += R4.z * g1; rg[3][1] += R4.w * g1;
            }
        }
        // reduce across the 4 row-groups holding the same column
        #pragma unroll
        for (int off = 16; off < 64; off <<= 1) {
            #pragma unroll
            for (int d = 0; d < 4; ++d) {
                rg[d][0] += __shfl_xor(rg[d][0], off, 64);
                rg[d][1] += __shfl_xor(rg[d][1], off, 64);
            }
        }
        if (kg == 0) {
            #pragma unroll
            for (int d = 0; d < 4; ++d) {
                RGl[d * 128 + wv * 32 + l15]      = rg[d][0];
                RGl[d * 128 + wv * 32 + 16 + l15] = rg[d][1];
            }
        }
    }
    __syncthreads();

    // ---- Phase 5: GRRG -> D ----------------------------------------------
    {
        int m = tid >> 1;
        int ab = (tid & 1) * 8;
        float rm0 = RGl[0 * 128 + m], rm1 = RGl[1 * 128 + m];
        float rm2 = RGl[2 * 128 + m], rm3 = RGl[3 * 128 + m];
        float outv[8];
        #pragma unroll
        for (int q = 0; q < 8; ++q) {
            int a = ab + q;
            outv[q] = rm0 * RGl[0 * 128 + a] + rm1 * RGl[1 * 128 + a]
                    + rm2 * RGl[2 * 128 + a] + rm3 * RGl[3 * 128 + a];
        }
        float4* dst = reinterpret_cast<float4*>(D + (size_t)p * DESC_ + m * 16 + ab);
        dst[0] = make_float4(outv[0], outv[1], outv[2], outv[3]);
        dst[1] = make_float4(outv[4], outv[5], outv[6], outv[7]);
    }
}

// ---------------------------------------------------------------------------
// One fitting layer: out[p][h] = tanh(sum_k in[p][k]*W[t][h][k] + bias[t][h])
// Block = (tile of <=64 type-pure atoms) x (64-h quarter). 4 waves, wave = 16 h.
// K-chunked (128) LDS staging of both operands; weights wave-uniform -> broadcast.
// ---------------------------------------------------------------------------
__global__ __launch_bounds__(256) void fit_kernel(
    const float* __restrict__ in,    // [4096][K]
    const float* __restrict__ W,     // [4][256][K]
    const float* __restrict__ bias,  // [4][256]
    float* __restrict__ out,         // [4096][256]
    int K,
    const int* __restrict__ meta)
{
    __shared__ float ldsD[128][64];  // [kk][atom]
    __shared__ float ldsW[128][64];  // [kk][h - hbB]

    int ntiles = meta[0];
    int tile = blockIdx.x >> 2;
    if (tile >= ntiles) return;
    int hq  = blockIdx.x & 3;
    int t   = __builtin_amdgcn_readfirstlane(meta[1 + tile * 3 + 0]);
    int p0  = meta[1 + tile * 3 + 1];
    int cnt = meta[1 + tile * 3 + 2];

    int tid = threadIdx.x;
    int a   = tid & 63;
    int wv  = tid >> 6;
    int hbB = hq * 64;
    int hbW = hbB + wv * 16;

    float acc[16];
    #pragma unroll
    for (int j = 0; j < 16; ++j) acc[j] = 0.f;

    int arow = p0 + a; if (arow > NATOMS - 1) arow = NATOMS - 1;
    const float* inrow = in + (size_t)arow * K;
    int hi  = tid >> 2;                 // 0..63 staging h
    int ksS = (tid & 3) * 32;           // staging k base
    const float* wrow = W + ((size_t)t * 256 + hbB + hi) * K;

    for (int k0 = 0; k0 < K; k0 += 128) {
        { // stage input chunk (transpose to [kk][a])
            const float4* s4 = reinterpret_cast<const float4*>(inrow + k0 + wv * 32);
            #pragma unroll
            for (int q4 = 0; q4 < 8; ++q4) {
                float4 v = s4[q4];
                int kk = wv * 32 + q4 * 4;
                ldsD[kk + 0][a] = v.x;
                ldsD[kk + 1][a] = v.y;
                ldsD[kk + 2][a] = v.z;
                ldsD[kk + 3][a] = v.w;
            }
        }
        { // stage weight chunk (transpose to [kk][h])
            const float4* s4 = reinterpret_cast<const float4*>(wrow + k0 + ksS);
            #pragma unroll
            for (int q4 = 0; q4 < 8; ++q4) {
                float4 v = s4[q4];
                int kk = ksS + q4 * 4;
                ldsW[kk + 0][hi] = v.x;
                ldsW[kk + 1][hi] = v.y;
                ldsW[kk + 2][hi] = v.z;
                ldsW[kk + 3][hi] = v.w;
            }
        }
        __syncthreads();
        #pragma unroll 4
        for (int kk = 0; kk < 128; ++kk) {
            float d = ldsD[kk][a];
            const float4* w4 = reinterpret_cast<const float4*>(&ldsW[kk][wv * 16]);
            #pragma unroll
            for (int j4 = 0; j4 < 4; ++j4) {
                float4 w = w4[j4];
                acc[j4 * 4 + 0] = fmaf(w.x, d, acc[j4 * 4 + 0]);
                acc[j4 * 4 + 1] = fmaf(w.y, d, acc[j4 * 4 + 1]);
                acc[j4 * 4 + 2] = fmaf(w.z, d, acc[j4 * 4 + 2]);
                acc[j4 * 4 + 3] = fmaf(w.w, d, acc[j4 * 4 + 3]);
            }
        }
        __syncthreads();
    }

    if (a < cnt) {
        float o[16];
        #pragma unroll
        for (int j = 0; j < 16; ++j)
            o[j] = fast_tanh(acc[j] + bias[t * 256 + hbW + j]);
        float4* dst = reinterpret_cast<float4*>(out + (size_t)(p0 + a) * 256 + hbW);
        dst[0] = make_float4(o[0], o[1], o[2], o[3]);
        dst[1] = make_float4(o[4], o[5], o[6], o[7]);
        dst[2] = make_float4(o[8], o[9], o[10], o[11]);
        dst[3] = make_float4(o[12], o[13], o[14], o[15]);
    }
}

// ---------------------------------------------------------------------------
// E_atom = h2 . Wo[t] + bo[t]; accumulate into out[b]. One wave per atom.
// ---------------------------------------------------------------------------
__global__ __launch_bounds__(256) void final_kernel(
    const float* __restrict__ h2, const int* __restrict__ perm,
    const int* __restrict__ types,
    const float* __restrict__ Wo, const float* __restrict__ bo,
    float* __restrict__ out)
{
    int tid = threadIdx.x;
    int wv = tid >> 6;
    int lane = tid & 63;
    int p = blockIdx.x * 4 + wv;
    int atom = perm[p];
    int t = types[atom];
    const float* hrow = h2 + (size_t)p * 256;
    float e = 0.f;
    #pragma unroll
    for (int r = 0; r < 4; ++r) {
        int h = r * 64 + lane;
        e += hrow[h] * Wo[t * 256 + h];
    }
    #pragma unroll
    for (int off = 32; off > 0; off >>= 1)
        e += __shfl_xor(e, off, 64);
    if (lane == 0) atomicAdd(&out[atom >> 9], e + bo[t]);
}

// ---------------------------------------------------------------------------
extern "C" void kernel_launch(void* const* d_in, const int* in_sizes, int n_in,
                              void* d_out, int out_size, void* d_ws, size_t ws_size,
                              hipStream_t stream) {
    const float* sym = (const float*)d_in[0];
    const int*   types = (const int*)d_in[1];
    const float* Wf0 = (const float*)d_in[2];
    const float* bf0 = (const float*)d_in[3];
    const float* Wf1 = (const float*)d_in[4];
    const float* bf1 = (const float*)d_in[5];
    const float* Wf2 = (const float*)d_in[6];
    const float* bf2 = (const float*)d_in[7];
    const float* Wt0 = (const float*)d_in[8];
    const float* bt0 = (const float*)d_in[9];
    const float* Wt1 = (const float*)d_in[10];
    const float* bt1 = (const float*)d_in[11];
    const float* Wt2 = (const float*)d_in[12];
    const float* bt2 = (const float*)d_in[13];
    const float* Wo  = (const float*)d_in[14];
    const float* bo  = (const float*)d_in[15];
    float* out = (float*)d_out;

    char* ws = (char*)d_ws;
    int*   meta = (int*)ws;                                     // 1 KB
    int*   perm = (int*)(ws + 1024);                            // 16 KB
    float* Dbuf = (float*)(ws + 32768);                         // 32 MB
    float* h0   = (float*)(ws + 32768 + (size_t)NATOMS * DESC_ * 4);
    float* h1   = h0 + (size_t)NATOMS * 256;
    float* h2   = h1 + (size_t)NATOMS * 256;

    hipMemsetAsync(d_out, 0, out_size * sizeof(float), stream);
    build_perm_kernel<<<1, 256, 0, stream>>>(types, perm, meta);
    filter_kernel<<<NATOMS, 256, 0, stream>>>(sym, types, perm,
                                              Wf0, bf0, Wf1, bf1, Wf2, bf2, Dbuf);
    fit_kernel<<<MAXTILES * 4, 256, 0, stream>>>(Dbuf, Wt0, bt0, h0, 2048, meta);
    fit_kernel<<<MAXTILES * 4, 256, 0, stream>>>(h0,   Wt1, bt1, h1, 256,  meta);
    fit_kernel<<<MAXTILES * 4, 256, 0, stream>>>(h1,   Wt2, bt2, h2, 256,  meta);
    final_kernel<<<NATOMS / 4, 256, 0, stream>>>(h2, perm, types, Wo, bo, out);
}

// Round 4
// 280.710 us; speedup vs baseline: 5.5236x; 1.4868x over previous
//
#include <hip/hip_runtime.h>
#include <hip/hip_bf16.h>

// Problem constants
#define NATOMS 4096     // B*N = 8*512
#define S_ 128
#define DESC_ 2048
#define H_ 256
#define MAXTILES 67     // sum ceil(cnt_t/64) <= 64+3

typedef short short8 __attribute__((ext_vector_type(8)));
typedef float f32x4 __attribute__((ext_vector_type(4)));
typedef unsigned short u16x8 __attribute__((ext_vector_type(8)));
typedef unsigned short u16x4 __attribute__((ext_vector_type(4)));
typedef unsigned short u16;

__device__ __forceinline__ float fast_tanh(float x) {
    float e = __expf(2.0f * x);
    return 1.0f - 2.0f * __frcp_rn(e + 1.0f);
}

__device__ __forceinline__ u16 f2bf(float f) {
    union { float f; unsigned int u; } v; v.f = f;
    unsigned int r = v.u + 0x7fffu + ((v.u >> 16) & 1u);
    return (u16)(r >> 16);
}
__device__ __forceinline__ float bf2f(u16 h) {
    union { unsigned int u; float f; } v; v.u = ((unsigned int)h) << 16;
    return v.f;
}
__device__ __forceinline__ void f2bf_split(float x, u16& hi, u16& lo) {
    hi = f2bf(x);
    lo = f2bf(x - bf2f(hi));
}

// ---------------------------------------------------------------------------
// Counting sort by type + 64-atom type-pure tiles.
// ---------------------------------------------------------------------------
__global__ __launch_bounds__(256) void build_perm_kernel(
    const int* __restrict__ types, int* __restrict__ perm, int* __restrict__ meta)
{
    __shared__ int cnt[256 * 4];
    __shared__ int tstart[5];
    int tid = threadIdx.x;
    int base = tid * 16;
    int c0 = 0, c1 = 0, c2 = 0, c3 = 0;
    for (int i = 0; i < 16; ++i) {
        int t = types[base + i];
        c0 += (t == 0); c1 += (t == 1); c2 += (t == 2); c3 += (t == 3);
    }
    cnt[tid * 4 + 0] = c0; cnt[tid * 4 + 1] = c1;
    cnt[tid * 4 + 2] = c2; cnt[tid * 4 + 3] = c3;
    __syncthreads();
    if (tid == 0) {
        int run = 0;
        for (int t = 0; t < 4; ++t) {
            tstart[t] = run;
            for (int th = 0; th < 256; ++th) {
                int v = cnt[th * 4 + t];
                cnt[th * 4 + t] = run;
                run += v;
            }
        }
        tstart[4] = run;
        int nt = 0;
        for (int t = 0; t < 4; ++t) {
            int cT = tstart[t + 1] - tstart[t];
            for (int off = 0; off < cT; off += 64) {
                meta[1 + nt * 3 + 0] = t;
                meta[1 + nt * 3 + 1] = tstart[t] + off;
                meta[1 + nt * 3 + 2] = (cT - off < 64) ? (cT - off) : 64;
                nt++;
            }
        }
        meta[0] = nt;
    }
    __syncthreads();
    for (int i = 0; i < 16; ++i) {
        int idx = base + i;
        int t = types[idx];
        perm[cnt[tid * 4 + t]++] = idx;
    }
}

// ---------------------------------------------------------------------------
// Split fp32 weights into hi/lo bf16 planes.
// ---------------------------------------------------------------------------
__global__ __launch_bounds__(256) void conv_kernel(
    const float* __restrict__ src, u16* __restrict__ dh, u16* __restrict__ dl, int n)
{
    int idx = (blockIdx.x * 256 + threadIdx.x) * 4;
    if (idx >= n) return;
    float4 v = *(const float4*)(src + idx);
    u16x4 oh, ol;
    u16 h, l;
    f2bf_split(v.x, h, l); oh[0] = h; ol[0] = l;
    f2bf_split(v.y, h, l); oh[1] = h; ol[1] = l;
    f2bf_split(v.z, h, l); oh[2] = h; ol[2] = l;
    f2bf_split(v.w, h, l); oh[3] = h; ol[3] = l;
    *(u16x4*)(dh + idx) = oh;
    *(u16x4*)(dl + idx) = ol;
}

// ---------------------------------------------------------------------------
// Filter net + descriptor per atom, split-bf16 MFMA. Writes D as hi/lo planes.
// ---------------------------------------------------------------------------
__global__ __launch_bounds__(256) void filter_kernel(
    const float* __restrict__ sym, const int* __restrict__ types,
    const int* __restrict__ perm,
    const float* __restrict__ Wf0, const float* __restrict__ bf0,
    const float* __restrict__ Wf1, const float* __restrict__ bf1,
    const float* __restrict__ Wf2, const float* __restrict__ bf2,
    u16* __restrict__ Dh, u16* __restrict__ Dl)
{
    __shared__ char lds[77824] __attribute__((aligned(16)));
    float*  Rl  = (float*)lds;                             // [128][4]
    u16* G1h = (u16*)(lds + 2048);   // [128][72]
    u16* G1l = (u16*)(lds + 20480);  // [128][72]
    u16* G0h = (u16*)(lds + 38912);  // [128][40]
    u16* G0l = (u16*)(lds + 49152);  // [128][40]
    u16* W1h = (u16*)(lds + 59392);  // [64][40]
    u16* W1l = (u16*)(lds + 64512);  // [64][40]
    u16* W2h = (u16*)(lds + 38912);  // [128][72]
    u16* W2l = (u16*)(lds + 57344);  // [128][72]
    float*  RGl = (float*)(lds + 75776);                   // [4][128]

    int p = blockIdx.x;
    int tid = threadIdx.x;
    int atom = perm[p];
    int t = __builtin_amdgcn_readfirstlane(types[atom]);
    int lane = tid & 63;
    int wv   = tid >> 6;
    int kg   = lane >> 4;
    int l15  = lane & 15;

    ((float2*)Rl)[tid] = ((const float2*)(sym + (size_t)atom * 512))[tid];
    {
        int e = tid * 8;
        const float4* s4 = (const float4*)(Wf1 + (size_t)t * 2048 + e);
        float4 v0 = s4[0], v1 = s4[1];
        float vv[8] = {v0.x, v0.y, v0.z, v0.w, v1.x, v1.y, v1.z, v1.w};
        u16x8 oh, ol;
        #pragma unroll
        for (int q = 0; q < 8; ++q) { u16 h, l; f2bf_split(vv[q], h, l); oh[q] = h; ol[q] = l; }
        int idx = (e >> 5) * 40 + (e & 31);
        *(u16x8*)&W1h[idx] = oh;
        *(u16x8*)&W1l[idx] = ol;
    }
    __syncthreads();

    // L0 -> G0 hi/lo
    {
        int s = tid >> 1;
        int f0 = (tid & 1) * 16;
        float sv = Rl[s * 4 + 0];
        u16x8 oh0, ol0, oh1, ol1;
        #pragma unroll
        for (int q = 0; q < 8; ++q) {
            u16 h, l;
            f2bf_split(fast_tanh(sv * Wf0[t * 32 + f0 + q] + bf0[t * 32 + f0 + q]), h, l);
            oh0[q] = h; ol0[q] = l;
        }
        #pragma unroll
        for (int q = 0; q < 8; ++q) {
            u16 h, l;
            f2bf_split(fast_tanh(sv * Wf0[t * 32 + f0 + 8 + q] + bf0[t * 32 + f0 + 8 + q]), h, l);
            oh1[q] = h; ol1[q] = l;
        }
        *(u16x8*)&G0h[s * 40 + f0]     = oh0;
        *(u16x8*)&G0l[s * 40 + f0]     = ol0;
        *(u16x8*)&G0h[s * 40 + f0 + 8] = oh1;
        *(u16x8*)&G0l[s * 40 + f0 + 8] = ol1;
    }
    __syncthreads();

    // L1 (K=32) -> G1 hi/lo
    {
        short8 b1h[4], b1l[4];
        float  bias1[4];
        #pragma unroll
        for (int nt = 0; nt < 4; ++nt) {
            int idx = (nt * 16 + l15) * 40 + kg * 8;
            b1h[nt] = *(const short8*)&W1h[idx];
            b1l[nt] = *(const short8*)&W1l[idx];
            bias1[nt] = bf1[t * 64 + nt * 16 + l15];
        }
        #pragma unroll
        for (int mi = 0; mi < 2; ++mi) {
            int mt = wv * 2 + mi;
            int aidx = (mt * 16 + l15) * 40 + kg * 8;
            short8 ah = *(const short8*)&G0h[aidx];
            short8 al = *(const short8*)&G0l[aidx];
            #pragma unroll
            for (int nt = 0; nt < 4; ++nt) {
                f32x4 acc = {0.f, 0.f, 0.f, 0.f};
                acc = __builtin_amdgcn_mfma_f32_16x16x32_bf16(ah, b1h[nt], acc, 0, 0, 0);
                acc = __builtin_amdgcn_mfma_f32_16x16x32_bf16(ah, b1l[nt], acc, 0, 0, 0);
                acc = __builtin_amdgcn_mfma_f32_16x16x32_bf16(al, b1h[nt], acc, 0, 0, 0);
                int rowb = mt * 16 + kg * 4;
                #pragma unroll
                for (int r = 0; r < 4; ++r) {
                    u16 h, l;
                    f2bf_split(fast_tanh(acc[r] + bias1[nt]), h, l);
                    G1h[(rowb + r) * 72 + nt * 16 + l15] = h;
                    G1l[(rowb + r) * 72 + nt * 16 + l15] = l;
                }
            }
        }
    }
    __syncthreads();

    // W2 -> hi/lo LDS
    {
        const float* Wsrc = Wf2 + (size_t)t * 8192;
        #pragma unroll
        for (int q = 0; q < 4; ++q) {
            int e = tid * 32 + q * 8;
            float4 v0 = *(const float4*)(Wsrc + e);
            float4 v1 = *(const float4*)(Wsrc + e + 4);
            float vv[8] = {v0.x, v0.y, v0.z, v0.w, v1.x, v1.y, v1.z, v1.w};
            u16x8 oh, ol;
            #pragma unroll
            for (int j = 0; j < 8; ++j) { u16 h, l; f2bf_split(vv[j], h, l); oh[j] = h; ol[j] = l; }
            int idx = (e >> 6) * 72 + (e & 63);
            *(u16x8*)&W2h[idx] = oh;
            *(u16x8*)&W2l[idx] = ol;
        }
    }
    __syncthreads();

    // L2 (K=64) fused with RG contraction
    {
        short8 b2h[2][2], b2l[2][2];
        float  bias2[2];
        #pragma unroll
        for (int ntl = 0; ntl < 2; ++ntl) {
            int nt = wv * 2 + ntl;
            bias2[ntl] = bf2[t * 128 + nt * 16 + l15];
            #pragma unroll
            for (int ks = 0; ks < 2; ++ks) {
                int idx = (nt * 16 + l15) * 72 + ks * 32 + kg * 8;
                b2h[ntl][ks] = *(const short8*)&W2h[idx];
                b2l[ntl][ks] = *(const short8*)&W2l[idx];
            }
        }
        float rg[4][2];
        #pragma unroll
        for (int d = 0; d < 4; ++d) { rg[d][0] = 0.f; rg[d][1] = 0.f; }

        #pragma unroll 2
        for (int mt = 0; mt < 8; ++mt) {
            int i0 = (mt * 16 + l15) * 72 + kg * 8;
            short8 a0h = *(const short8*)&G1h[i0];
            short8 a0l = *(const short8*)&G1l[i0];
            short8 a1h = *(const short8*)&G1h[i0 + 32];
            short8 a1l = *(const short8*)&G1l[i0 + 32];
            f32x4 acc0 = {0.f,0.f,0.f,0.f}, acc1 = {0.f,0.f,0.f,0.f};
            acc0 = __builtin_amdgcn_mfma_f32_16x16x32_bf16(a0h, b2h[0][0], acc0, 0,0,0);
            acc0 = __builtin_amdgcn_mfma_f32_16x16x32_bf16(a0h, b2l[0][0], acc0, 0,0,0);
            acc0 = __builtin_amdgcn_mfma_f32_16x16x32_bf16(a0l, b2h[0][0], acc0, 0,0,0);
            acc0 = __builtin_amdgcn_mfma_f32_16x16x32_bf16(a1h, b2h[0][1], acc0, 0,0,0);
            acc0 = __builtin_amdgcn_mfma_f32_16x16x32_bf16(a1h, b2l[0][1], acc0, 0,0,0);
            acc0 = __builtin_amdgcn_mfma_f32_16x16x32_bf16(a1l, b2h[0][1], acc0, 0,0,0);
            acc1 = __builtin_amdgcn_mfma_f32_16x16x32_bf16(a0h, b2h[1][0], acc1, 0,0,0);
            acc1 = __builtin_amdgcn_mfma_f32_16x16x32_bf16(a0h, b2l[1][0], acc1, 0,0,0);
            acc1 = __builtin_amdgcn_mfma_f32_16x16x32_bf16(a0l, b2h[1][0], acc1, 0,0,0);
            acc1 = __builtin_amdgcn_mfma_f32_16x16x32_bf16(a1h, b2h[1][1], acc1, 0,0,0);
            acc1 = __builtin_amdgcn_mfma_f32_16x16x32_bf16(a1h, b2l[1][1], acc1, 0,0,0);
            acc1 = __builtin_amdgcn_mfma_f32_16x16x32_bf16(a1l, b2h[1][1], acc1, 0,0,0);
            int rowb = mt * 16 + kg * 4;
            #pragma unroll
            for (int r = 0; r < 4; ++r) {
                float4 R4 = *(const float4*)&Rl[(rowb + r) * 4];
                float g0 = fast_tanh(acc0[r] + bias2[0]);
                float g1 = fast_tanh(acc1[r] + bias2[1]);
                rg[0][0] += R4.x * g0; rg[1][0] += R4.y * g0;
                rg[2][0] += R4.z * g0; rg[3][0] += R4.w * g0;
                rg[0][1] += R4.x * g1; rg[1][1] += R4.y * g1;
                rg[2][1] += R4.z * g1; rg[3][1] += R4.w * g1;
            }
        }
        #pragma unroll
        for (int off = 16; off < 64; off <<= 1) {
            #pragma unroll
            for (int d = 0; d < 4; ++d) {
                rg[d][0] += __shfl_xor(rg[d][0], off, 64);
                rg[d][1] += __shfl_xor(rg[d][1], off, 64);
            }
        }
        if (kg == 0) {
            #pragma unroll
            for (int d = 0; d < 4; ++d) {
                RGl[d * 128 + wv * 32 + l15]      = rg[d][0];
                RGl[d * 128 + wv * 32 + 16 + l15] = rg[d][1];
            }
        }
    }
    __syncthreads();

    // GRRG -> D hi/lo planes
    {
        int m = tid >> 1;
        int ab = (tid & 1) * 8;
        float rm0 = RGl[0 * 128 + m], rm1 = RGl[1 * 128 + m];
        float rm2 = RGl[2 * 128 + m], rm3 = RGl[3 * 128 + m];
        u16x8 oh, ol;
        #pragma unroll
        for (int q = 0; q < 8; ++q) {
            int a = ab + q;
            float v = rm0 * RGl[0 * 128 + a] + rm1 * RGl[1 * 128 + a]
                    + rm2 * RGl[2 * 128 + a] + rm3 * RGl[3 * 128 + a];
            u16 h, l; f2bf_split(v, h, l);
            oh[q] = h; ol[q] = l;
        }
        size_t base = (size_t)p * DESC_ + m * 16 + ab;
        *(u16x8*)(Dh + base) = oh;
        *(u16x8*)(Dl + base) = ol;
    }
}

// ---------------------------------------------------------------------------
// MFMA fitting layer: out[p][h] = tanh(sum_k in[p][k]*W[t][h][k] + bias[t][h])
// in/W/out are hi/lo bf16 planes. Block = 64 atoms x 128 h (grid = 2*ntiles).
// 4 waves; wave = 64a x 32h = 4 m-tiles x 2 n-tiles. KC=64 chunks.
// LDS rows padded to 72 elems (144 B) -> 2-way bank aliasing only.
// ---------------------------------------------------------------------------
__global__ __launch_bounds__(256) void fit_mfma(
    const u16* __restrict__ inh, const u16* __restrict__ inl,
    const u16* __restrict__ Wh,  const u16* __restrict__ Wl,
    const float* __restrict__ bias,
    u16* __restrict__ outh, u16* __restrict__ outl,
    int K, const int* __restrict__ meta)
{
    __shared__ u16 Ath[64 * 72];
    __shared__ u16 Atl[64 * 72];
    __shared__ u16 Bth[128 * 72];
    __shared__ u16 Btl[128 * 72];

    int ntiles = meta[0];
    int tile = blockIdx.x >> 1;
    if (tile >= ntiles) return;
    int hhalf = blockIdx.x & 1;
    int t   = __builtin_amdgcn_readfirstlane(meta[1 + tile * 3 + 0]);
    int p0  = meta[1 + tile * 3 + 1];
    int cnt = meta[1 + tile * 3 + 2];
    int h0b = hhalf * 128;

    int tid = threadIdx.x;
    int lane = tid & 63;
    int wv   = tid >> 6;
    int kg   = lane >> 4;
    int l15  = lane & 15;

    // staging coords
    int srow = tid >> 2;          // 0..63
    int skc  = (tid & 3) * 16;    // k offset within chunk
    int agrow = p0 + srow; if (agrow > NATOMS - 1) agrow = NATOMS - 1;
    const u16* arow_h = inh + (size_t)agrow * K;
    const u16* arow_l = inl + (size_t)agrow * K;
    const u16* brow_h0 = Wh + ((size_t)t * 256 + h0b + srow) * K;
    const u16* brow_l0 = Wl + ((size_t)t * 256 + h0b + srow) * K;
    const u16* brow_h1 = Wh + ((size_t)t * 256 + h0b + 64 + srow) * K;
    const u16* brow_l1 = Wl + ((size_t)t * 256 + h0b + 64 + srow) * K;

    f32x4 acc[4][2];
    #pragma unroll
    for (int mt = 0; mt < 4; ++mt)
        #pragma unroll
        for (int nt = 0; nt < 2; ++nt)
            acc[mt][nt] = (f32x4){0.f, 0.f, 0.f, 0.f};

    for (int k0 = 0; k0 < K; k0 += 64) {
        // ---- stage A (64x64 hi/lo) and B (128x64 hi/lo) ----
        {
            u16x8 a0 = *(const u16x8*)(arow_h + k0 + skc);
            u16x8 a1 = *(const u16x8*)(arow_h + k0 + skc + 8);
            u16x8 a2 = *(const u16x8*)(arow_l + k0 + skc);
            u16x8 a3 = *(const u16x8*)(arow_l + k0 + skc + 8);
            u16x8 b0 = *(const u16x8*)(brow_h0 + k0 + skc);
            u16x8 b1 = *(const u16x8*)(brow_h0 + k0 + skc + 8);
            u16x8 b2 = *(const u16x8*)(brow_l0 + k0 + skc);
            u16x8 b3 = *(const u16x8*)(brow_l0 + k0 + skc + 8);
            u16x8 b4 = *(const u16x8*)(brow_h1 + k0 + skc);
            u16x8 b5 = *(const u16x8*)(brow_h1 + k0 + skc + 8);
            u16x8 b6 = *(const u16x8*)(brow_l1 + k0 + skc);
            u16x8 b7 = *(const u16x8*)(brow_l1 + k0 + skc + 8);
            __syncthreads();   // previous chunk's reads done
            int ai = srow * 72 + skc;
            *(u16x8*)&Ath[ai]     = a0;
            *(u16x8*)&Ath[ai + 8] = a1;
            *(u16x8*)&Atl[ai]     = a2;
            *(u16x8*)&Atl[ai + 8] = a3;
            int bi0 = srow * 72 + skc;
            int bi1 = (srow + 64) * 72 + skc;
            *(u16x8*)&Bth[bi0]     = b0;
            *(u16x8*)&Bth[bi0 + 8] = b1;
            *(u16x8*)&Btl[bi0]     = b2;
            *(u16x8*)&Btl[bi0 + 8] = b3;
            *(u16x8*)&Bth[bi1]     = b4;
            *(u16x8*)&Bth[bi1 + 8] = b5;
            *(u16x8*)&Btl[bi1]     = b6;
            *(u16x8*)&Btl[bi1 + 8] = b7;
        }
        __syncthreads();

        // ---- compute: 2 k-steps of 32 ----
        #pragma unroll
        for (int ks = 0; ks < 2; ++ks) {
            short8 bh[2], bl[2];
            #pragma unroll
            for (int nt = 0; nt < 2; ++nt) {
                int bi = (wv * 32 + nt * 16 + l15) * 72 + ks * 32 + kg * 8;
                bh[nt] = *(const short8*)&Bth[bi];
                bl[nt] = *(const short8*)&Btl[bi];
            }
            #pragma unroll
            for (int mt = 0; mt < 4; ++mt) {
                int ai = (mt * 16 + l15) * 72 + ks * 32 + kg * 8;
                short8 ah = *(const short8*)&Ath[ai];
                short8 al = *(const short8*)&Atl[ai];
                #pragma unroll
                for (int nt = 0; nt < 2; ++nt) {
                    acc[mt][nt] = __builtin_amdgcn_mfma_f32_16x16x32_bf16(ah, bh[nt], acc[mt][nt], 0, 0, 0);
                    acc[mt][nt] = __builtin_amdgcn_mfma_f32_16x16x32_bf16(ah, bl[nt], acc[mt][nt], 0, 0, 0);
                    acc[mt][nt] = __builtin_amdgcn_mfma_f32_16x16x32_bf16(al, bh[nt], acc[mt][nt], 0, 0, 0);
                }
            }
        }
    }

    // ---- epilogue: tanh + bias, write hi/lo planes ----
    #pragma unroll
    for (int mt = 0; mt < 4; ++mt) {
        #pragma unroll
        for (int nt = 0; nt < 2; ++nt) {
            int h = h0b + wv * 32 + nt * 16 + l15;
            float b = bias[t * 256 + h];
            #pragma unroll
            for (int r = 0; r < 4; ++r) {
                int al = mt * 16 + kg * 4 + r;
                if (al < cnt) {
                    float v = fast_tanh(acc[mt][nt][r] + b);
                    u16 hh, ll; f2bf_split(v, hh, ll);
                    size_t o = (size_t)(p0 + al) * 256 + h;
                    outh[o] = hh;
                    outl[o] = ll;
                }
            }
        }
    }
}

// ---------------------------------------------------------------------------
// E_atom = h2 . Wo[t] + bo[t]; accumulate into out[b]. One wave per atom.
// ---------------------------------------------------------------------------
__global__ __launch_bounds__(256) void final_kernel(
    const u16* __restrict__ h2h, const u16* __restrict__ h2l,
    const int* __restrict__ perm, const int* __restrict__ types,
    const float* __restrict__ Wo, const float* __restrict__ bo,
    float* __restrict__ out)
{
    int tid = threadIdx.x;
    int wv = tid >> 6;
    int lane = tid & 63;
    int p = blockIdx.x * 4 + wv;
    int atom = perm[p];
    int t = types[atom];
    const u16* hh = h2h + (size_t)p * 256;
    const u16* hl = h2l + (size_t)p * 256;
    float e = 0.f;
    #pragma unroll
    for (int r = 0; r < 4; ++r) {
        int h = r * 64 + lane;
        e += (bf2f(hh[h]) + bf2f(hl[h])) * Wo[t * 256 + h];
    }
    #pragma unroll
    for (int off = 32; off > 0; off >>= 1)
        e += __shfl_xor(e, off, 64);
    if (lane == 0) atomicAdd(&out[atom >> 9], e + bo[t]);
}

// ---------------------------------------------------------------------------
extern "C" void kernel_launch(void* const* d_in, const int* in_sizes, int n_in,
                              void* d_out, int out_size, void* d_ws, size_t ws_size,
                              hipStream_t stream) {
    const float* sym = (const float*)d_in[0];
    const int*   types = (const int*)d_in[1];
    const float* Wf0 = (const float*)d_in[2];
    const float* bf0 = (const float*)d_in[3];
    const float* Wf1 = (const float*)d_in[4];
    const float* bf1 = (const float*)d_in[5];
    const float* Wf2 = (const float*)d_in[6];
    const float* bf2 = (const float*)d_in[7];
    const float* Wt0 = (const float*)d_in[8];
    const float* bt0 = (const float*)d_in[9];
    const float* Wt1 = (const float*)d_in[10];
    const float* bt1 = (const float*)d_in[11];
    const float* Wt2 = (const float*)d_in[12];
    const float* bt2 = (const float*)d_in[13];
    const float* Wo  = (const float*)d_in[14];
    const float* bo  = (const float*)d_in[15];
    float* out = (float*)d_out;

    char* ws = (char*)d_ws;
    const size_t MB = 1024 * 1024;
    int*  meta = (int*)ws;                          // 1 KB
    int*  perm = (int*)(ws + 1024);                 // 16 KB
    u16*  Dh   = (u16*)(ws + 32768);                // 16 MB (4096*2048*2)
    u16*  Dl   = (u16*)(ws + 32768 + 16 * MB);      // 16 MB
    u16*  h0h  = (u16*)(ws + 32768 + 32 * MB);      // 2 MB each
    u16*  h0l  = (u16*)(ws + 32768 + 34 * MB);
    u16*  h1h  = (u16*)(ws + 32768 + 36 * MB);
    u16*  h1l  = (u16*)(ws + 32768 + 38 * MB);
    u16*  h2h  = (u16*)(ws + 32768 + 40 * MB);
    u16*  h2l  = (u16*)(ws + 32768 + 42 * MB);
    u16*  W0h  = (u16*)(ws + 32768 + 44 * MB);      // 4 MB each
    u16*  W0l  = (u16*)(ws + 32768 + 48 * MB);
    u16*  W1h  = (u16*)(ws + 32768 + 52 * MB);      // 512 KB each
    u16*  W1l  = (u16*)(ws + 32768 + 52 * MB + 512 * 1024);
    u16*  W2h  = (u16*)(ws + 32768 + 53 * MB);
    u16*  W2l  = (u16*)(ws + 32768 + 53 * MB + 512 * 1024);

    hipMemsetAsync(d_out, 0, out_size * sizeof(float), stream);
    build_perm_kernel<<<1, 256, 0, stream>>>(types, perm, meta);

    // weight conversion (hi/lo planes)
    conv_kernel<<<2048, 256, 0, stream>>>(Wt0, W0h, W0l, 4 * 256 * 2048);
    conv_kernel<<<256,  256, 0, stream>>>(Wt1, W1h, W1l, 4 * 256 * 256);
    conv_kernel<<<256,  256, 0, stream>>>(Wt2, W2h, W2l, 4 * 256 * 256);

    filter_kernel<<<NATOMS, 256, 0, stream>>>(sym, types, perm,
                                              Wf0, bf0, Wf1, bf1, Wf2, bf2, Dh, Dl);

    fit_mfma<<<MAXTILES * 2, 256, 0, stream>>>(Dh,  Dl,  W0h, W0l, bt0, h0h, h0l, 2048, meta);
    fit_mfma<<<MAXTILES * 2, 256, 0, stream>>>(h0h, h0l, W1h, W1l, bt1, h1h, h1l, 256,  meta);
    fit_mfma<<<MAXTILES * 2, 256, 0, stream>>>(h1h, h1l, W2h, W2l, bt2, h2h, h2l, 256,  meta);
    final_kernel<<<NATOMS / 4, 256, 0, stream>>>(h2h, h2l, perm, types, Wo, bo, out);
}

// Round 5
// 232.535 us; speedup vs baseline: 6.6679x; 1.2072x over previous
//
#include <hip/hip_runtime.h>
#include <hip/hip_bf16.h>

// Problem constants
#define NATOMS 4096     // B*N = 8*512
#define S_ 128
#define DESC_ 2048
#define H_ 256
#define MAXTILES 67     // sum ceil(cnt_t/64) <= 64+3

typedef short short8 __attribute__((ext_vector_type(8)));
typedef float f32x4 __attribute__((ext_vector_type(4)));
typedef unsigned short u16x8 __attribute__((ext_vector_type(8)));
typedef unsigned short u16x4 __attribute__((ext_vector_type(4)));
typedef unsigned short u16;

__device__ __forceinline__ float fast_tanh(float x) {
    // tanh(x) = 1 - 2/(exp(2x)+1); raw v_rcp (1 ulp) is plenty here
    float e = __expf(2.0f * x);
    return 1.0f - 2.0f * __builtin_amdgcn_rcpf(e + 1.0f);
}

__device__ __forceinline__ float bf2f(u16 h) {
    union { unsigned int u; float f; } v; v.u = ((unsigned int)h) << 16;
    return v.f;
}
// truncation split: x ~= hi + lo to ~2^-15 rel, 3 VALU ops
__device__ __forceinline__ void f2bf_split(float x, u16& hi, u16& lo) {
    union { float f; unsigned int u; } v; v.f = x;
    unsigned int hb = v.u & 0xffff0000u;
    hi = (u16)(hb >> 16);
    union { unsigned int u; float f; } w; w.u = hb;
    union { float f; unsigned int u; } z; z.f = x - w.f;
    lo = (u16)(z.u >> 16);
}

// ---------------------------------------------------------------------------
// Counting sort by type + 64-atom type-pure tiles.
// ---------------------------------------------------------------------------
__global__ __launch_bounds__(256) void build_perm_kernel(
    const int* __restrict__ types, int* __restrict__ perm, int* __restrict__ meta)
{
    __shared__ int cnt[256 * 4];
    __shared__ int tot[4];
    __shared__ int tstart[4];
    int tid = threadIdx.x;
    int base = tid * 16;
    int c0 = 0, c1 = 0, c2 = 0, c3 = 0;
    for (int i = 0; i < 16; ++i) {
        int t = types[base + i];
        c0 += (t == 0); c1 += (t == 1); c2 += (t == 2); c3 += (t == 3);
    }
    cnt[tid * 4 + 0] = c0; cnt[tid * 4 + 1] = c1;
    cnt[tid * 4 + 2] = c2; cnt[tid * 4 + 3] = c3;
    __syncthreads();
    if (tid < 4) {   // per-type exclusive scan, one lane per type
        int run = 0;
        for (int th = 0; th < 256; ++th) {
            int v = cnt[th * 4 + tid];
            cnt[th * 4 + tid] = run;
            run += v;
        }
        tot[tid] = run;
    }
    __syncthreads();
    if (tid == 0) {
        int run = 0, nt = 0;
        for (int t = 0; t < 4; ++t) { tstart[t] = run; run += tot[t]; }
        for (int t = 0; t < 4; ++t) {
            int cT = tot[t];
            for (int off = 0; off < cT; off += 64) {
                meta[1 + nt * 3 + 0] = t;
                meta[1 + nt * 3 + 1] = tstart[t] + off;
                meta[1 + nt * 3 + 2] = (cT - off < 64) ? (cT - off) : 64;
                nt++;
            }
        }
        meta[0] = nt;
    }
    __syncthreads();
    for (int i = 0; i < 16; ++i) {
        int idx = base + i;
        int t = types[idx];
        perm[tstart[t] + cnt[tid * 4 + t]++] = idx;
    }
}

// ---------------------------------------------------------------------------
// Split fp32 array into hi/lo bf16 planes.
// ---------------------------------------------------------------------------
__global__ __launch_bounds__(256) void conv_kernel(
    const float* __restrict__ src, u16* __restrict__ dh, u16* __restrict__ dl, int n)
{
    int idx = (blockIdx.x * 256 + threadIdx.x) * 4;
    if (idx >= n) return;
    float4 v = *(const float4*)(src + idx);
    u16x4 oh, ol;
    u16 h, l;
    f2bf_split(v.x, h, l); oh[0] = h; ol[0] = l;
    f2bf_split(v.y, h, l); oh[1] = h; ol[1] = l;
    f2bf_split(v.z, h, l); oh[2] = h; ol[2] = l;
    f2bf_split(v.w, h, l); oh[3] = h; ol[3] = l;
    *(u16x4*)(dh + idx) = oh;
    *(u16x4*)(dl + idx) = ol;
}

// ---------------------------------------------------------------------------
// Filter net + descriptor per atom, split-bf16 MFMA.
// Weight B-fragments read directly from pre-split global planes (L2-hit).
// LDS 61440 B:
//   Rl  [128][4] f32 @0   G0h [128][40] @2048   G0l @12288
//   G1h [128][72] @22528  G1l @40960            RGl [4][128] f32 @59392
// ---------------------------------------------------------------------------
__global__ __launch_bounds__(256) void filter_kernel(
    const float* __restrict__ sym, const int* __restrict__ types,
    const int* __restrict__ perm,
    const float* __restrict__ Wf0, const float* __restrict__ bf0,
    const u16* __restrict__ F1h, const u16* __restrict__ F1l,
    const float* __restrict__ bf1,
    const u16* __restrict__ F2h, const u16* __restrict__ F2l,
    const float* __restrict__ bf2,
    u16* __restrict__ Dh, u16* __restrict__ Dl)
{
    __shared__ char lds[61440] __attribute__((aligned(16)));
    float* Rl  = (float*)lds;            // [128][4]
    u16*   G0h = (u16*)(lds + 2048);     // [128][40]
    u16*   G0l = (u16*)(lds + 12288);
    u16*   G1h = (u16*)(lds + 22528);    // [128][72]
    u16*   G1l = (u16*)(lds + 40960);
    float* RGl = (float*)(lds + 59392);  // [4][128]

    int p = blockIdx.x;
    int tid = threadIdx.x;
    int atom = perm[p];
    int t = __builtin_amdgcn_readfirstlane(types[atom]);
    int lane = tid & 63;
    int wv   = tid >> 6;
    int kg   = lane >> 4;
    int l15  = lane & 15;

    // ---- Phase 0+1: load R; L0 -> G0 hi/lo (sv from global, no barrier) ---
    ((float2*)Rl)[tid] = ((const float2*)(sym + (size_t)atom * 512))[tid];
    {
        int s = tid >> 1;
        int f0 = (tid & 1) * 16;
        float sv = sym[(size_t)atom * 512 + s * 4];   // same cache line as above
        const float4* wp = (const float4*)(Wf0 + t * 32 + f0);
        const float4* bp = (const float4*)(bf0 + t * 32 + f0);
        u16 oh[16], ol[16];
        #pragma unroll
        for (int q4 = 0; q4 < 4; ++q4) {
            float4 w4 = wp[q4];
            float4 b4 = bp[q4];
            u16 h, l;
            f2bf_split(fast_tanh(sv * w4.x + b4.x), h, l); oh[q4*4+0]=h; ol[q4*4+0]=l;
            f2bf_split(fast_tanh(sv * w4.y + b4.y), h, l); oh[q4*4+1]=h; ol[q4*4+1]=l;
            f2bf_split(fast_tanh(sv * w4.z + b4.z), h, l); oh[q4*4+2]=h; ol[q4*4+2]=l;
            f2bf_split(fast_tanh(sv * w4.w + b4.w), h, l); oh[q4*4+3]=h; ol[q4*4+3]=l;
        }
        u16x8 vh0, vh1, vl0, vl1;
        #pragma unroll
        for (int q = 0; q < 8; ++q) { vh0[q]=oh[q]; vh1[q]=oh[q+8]; vl0[q]=ol[q]; vl1[q]=ol[q+8]; }
        *(u16x8*)&G0h[s * 40 + f0]     = vh0;
        *(u16x8*)&G0h[s * 40 + f0 + 8] = vh1;
        *(u16x8*)&G0l[s * 40 + f0]     = vl0;
        *(u16x8*)&G0l[s * 40 + f0 + 8] = vl1;
    }
    __syncthreads();

    // ---- Phase 2: L1 (K=32) -> G1 hi/lo; B-fragments from global ---------
    {
        short8 b1h[4], b1l[4];
        float  bias1[4];
        #pragma unroll
        for (int nt = 0; nt < 4; ++nt) {
            int off = t * 2048 + (nt * 16 + l15) * 32 + kg * 8;
            b1h[nt] = *(const short8*)(F1h + off);
            b1l[nt] = *(const short8*)(F1l + off);
            bias1[nt] = bf1[t * 64 + nt * 16 + l15];
        }
        #pragma unroll
        for (int mi = 0; mi < 2; ++mi) {
            int mt = wv * 2 + mi;
            int aidx = (mt * 16 + l15) * 40 + kg * 8;
            short8 ah = *(const short8*)&G0h[aidx];
            short8 al = *(const short8*)&G0l[aidx];
            #pragma unroll
            for (int nt = 0; nt < 4; ++nt) {
                f32x4 acc = {0.f, 0.f, 0.f, 0.f};
                acc = __builtin_amdgcn_mfma_f32_16x16x32_bf16(ah, b1h[nt], acc, 0, 0, 0);
                acc = __builtin_amdgcn_mfma_f32_16x16x32_bf16(ah, b1l[nt], acc, 0, 0, 0);
                acc = __builtin_amdgcn_mfma_f32_16x16x32_bf16(al, b1h[nt], acc, 0, 0, 0);
                int rowb = mt * 16 + kg * 4;
                #pragma unroll
                for (int r = 0; r < 4; ++r) {
                    u16 h, l;
                    f2bf_split(fast_tanh(acc[r] + bias1[nt]), h, l);
                    G1h[(rowb + r) * 72 + nt * 16 + l15] = h;
                    G1l[(rowb + r) * 72 + nt * 16 + l15] = l;
                }
            }
        }
    }
    __syncthreads();

    // ---- Phase 4: L2 (K=64) fused with RG contraction --------------------
    {
        short8 b2h[2][2], b2l[2][2];
        float  bias2[2];
        #pragma unroll
        for (int ntl = 0; ntl < 2; ++ntl) {
            int nt = wv * 2 + ntl;
            bias2[ntl] = bf2[t * 128 + nt * 16 + l15];
            #pragma unroll
            for (int ks = 0; ks < 2; ++ks) {
                int off = t * 8192 + (nt * 16 + l15) * 64 + ks * 32 + kg * 8;
                b2h[ntl][ks] = *(const short8*)(F2h + off);
                b2l[ntl][ks] = *(const short8*)(F2l + off);
            }
        }
        float rg[4][2];
        #pragma unroll
        for (int d = 0; d < 4; ++d) { rg[d][0] = 0.f; rg[d][1] = 0.f; }

        #pragma unroll 2
        for (int mt = 0; mt < 8; ++mt) {
            int i0 = (mt * 16 + l15) * 72 + kg * 8;
            short8 a0h = *(const short8*)&G1h[i0];
            short8 a0l = *(const short8*)&G1l[i0];
            short8 a1h = *(const short8*)&G1h[i0 + 32];
            short8 a1l = *(const short8*)&G1l[i0 + 32];
            f32x4 acc0 = {0.f,0.f,0.f,0.f}, acc1 = {0.f,0.f,0.f,0.f};
            acc0 = __builtin_amdgcn_mfma_f32_16x16x32_bf16(a0h, b2h[0][0], acc0, 0,0,0);
            acc0 = __builtin_amdgcn_mfma_f32_16x16x32_bf16(a0h, b2l[0][0], acc0, 0,0,0);
            acc0 = __builtin_amdgcn_mfma_f32_16x16x32_bf16(a0l, b2h[0][0], acc0, 0,0,0);
            acc0 = __builtin_amdgcn_mfma_f32_16x16x32_bf16(a1h, b2h[0][1], acc0, 0,0,0);
            acc0 = __builtin_amdgcn_mfma_f32_16x16x32_bf16(a1h, b2l[0][1], acc0, 0,0,0);
            acc0 = __builtin_amdgcn_mfma_f32_16x16x32_bf16(a1l, b2h[0][1], acc0, 0,0,0);
            acc1 = __builtin_amdgcn_mfma_f32_16x16x32_bf16(a0h, b2h[1][0], acc1, 0,0,0);
            acc1 = __builtin_amdgcn_mfma_f32_16x16x32_bf16(a0h, b2l[1][0], acc1, 0,0,0);
            acc1 = __builtin_amdgcn_mfma_f32_16x16x32_bf16(a0l, b2h[1][0], acc1, 0,0,0);
            acc1 = __builtin_amdgcn_mfma_f32_16x16x32_bf16(a1h, b2h[1][1], acc1, 0,0,0);
            acc1 = __builtin_amdgcn_mfma_f32_16x16x32_bf16(a1h, b2l[1][1], acc1, 0,0,0);
            acc1 = __builtin_amdgcn_mfma_f32_16x16x32_bf16(a1l, b2h[1][1], acc1, 0,0,0);
            int rowb = mt * 16 + kg * 4;
            #pragma unroll
            for (int r = 0; r < 4; ++r) {
                float4 R4 = *(const float4*)&Rl[(rowb + r) * 4];
                float g0 = fast_tanh(acc0[r] + bias2[0]);
                float g1 = fast_tanh(acc1[r] + bias2[1]);
                rg[0][0] += R4.x * g0; rg[1][0] += R4.y * g0;
                rg[2][0] += R4.z * g0; rg[3][0] += R4.w * g0;
                rg[0][1] += R4.x * g1; rg[1][1] += R4.y * g1;
                rg[2][1] += R4.z * g1; rg[3][1] += R4.w * g1;
            }
        }
        #pragma unroll
        for (int off = 16; off < 64; off <<= 1) {
            #pragma unroll
            for (int d = 0; d < 4; ++d) {
                rg[d][0] += __shfl_xor(rg[d][0], off, 64);
                rg[d][1] += __shfl_xor(rg[d][1], off, 64);
            }
        }
        if (kg == 0) {
            #pragma unroll
            for (int d = 0; d < 4; ++d) {
                RGl[d * 128 + wv * 32 + l15]      = rg[d][0];
                RGl[d * 128 + wv * 32 + 16 + l15] = rg[d][1];
            }
        }
    }
    __syncthreads();

    // ---- Phase 5: GRRG -> D hi/lo planes ---------------------------------
    {
        int m = tid >> 1;
        int ab = (tid & 1) * 8;
        float rm0 = RGl[0 * 128 + m], rm1 = RGl[1 * 128 + m];
        float rm2 = RGl[2 * 128 + m], rm3 = RGl[3 * 128 + m];
        u16x8 oh, ol;
        #pragma unroll
        for (int q = 0; q < 8; ++q) {
            int a = ab + q;
            float v = rm0 * RGl[0 * 128 + a] + rm1 * RGl[1 * 128 + a]
                    + rm2 * RGl[2 * 128 + a] + rm3 * RGl[3 * 128 + a];
            u16 h, l; f2bf_split(v, h, l);
            oh[q] = h; ol[q] = l;
        }
        size_t base = (size_t)p * DESC_ + m * 16 + ab;
        *(u16x8*)(Dh + base) = oh;
        *(u16x8*)(Dl + base) = ol;
    }
}

// ---------------------------------------------------------------------------
// MFMA fitting layer. Block = 64 atoms x 64 h. grid = MAXTILES*4 (all CUs).
// 4 waves; wave = 64a x 16h = 4 m-tiles. KC=64 chunks, LDS 36 KB -> 4 blk/CU.
// ---------------------------------------------------------------------------
__global__ __launch_bounds__(256) void fit_mfma(
    const u16* __restrict__ inh, const u16* __restrict__ inl,
    const u16* __restrict__ Wh,  const u16* __restrict__ Wl,
    const float* __restrict__ bias,
    u16* __restrict__ outh, u16* __restrict__ outl,
    int K, const int* __restrict__ meta)
{
    __shared__ char lds[36864] __attribute__((aligned(16)));
    u16* Ath = (u16*)lds;             // [64][72]
    u16* Atl = (u16*)(lds + 9216);
    u16* Bth = (u16*)(lds + 18432);   // [64][72]
    u16* Btl = (u16*)(lds + 27648);

    int ntiles = meta[0];
    int tile = blockIdx.x >> 2;
    if (tile >= ntiles) return;
    int hq  = blockIdx.x & 3;
    int t   = __builtin_amdgcn_readfirstlane(meta[1 + tile * 3 + 0]);
    int p0  = meta[1 + tile * 3 + 1];
    int cnt = meta[1 + tile * 3 + 2];
    int h0b = hq * 64;

    int tid = threadIdx.x;
    int lane = tid & 63;
    int wv   = tid >> 6;
    int kg   = lane >> 4;
    int l15  = lane & 15;

    int srow = tid >> 2;          // 0..63
    int skc  = (tid & 3) * 16;    // k offset within chunk
    int agrow = p0 + srow; if (agrow > NATOMS - 1) agrow = NATOMS - 1;
    const u16* arow_h = inh + (size_t)agrow * K;
    const u16* arow_l = inl + (size_t)agrow * K;
    const u16* brow_h = Wh + ((size_t)t * 256 + h0b + srow) * K;
    const u16* brow_l = Wl + ((size_t)t * 256 + h0b + srow) * K;

    f32x4 acc[4];
    #pragma unroll
    for (int mt = 0; mt < 4; ++mt) acc[mt] = (f32x4){0.f, 0.f, 0.f, 0.f};

    for (int k0 = 0; k0 < K; k0 += 64) {
        u16x8 a0 = *(const u16x8*)(arow_h + k0 + skc);
        u16x8 a1 = *(const u16x8*)(arow_h + k0 + skc + 8);
        u16x8 a2 = *(const u16x8*)(arow_l + k0 + skc);
        u16x8 a3 = *(const u16x8*)(arow_l + k0 + skc + 8);
        u16x8 b0 = *(const u16x8*)(brow_h + k0 + skc);
        u16x8 b1 = *(const u16x8*)(brow_h + k0 + skc + 8);
        u16x8 b2 = *(const u16x8*)(brow_l + k0 + skc);
        u16x8 b3 = *(const u16x8*)(brow_l + k0 + skc + 8);
        __syncthreads();   // previous chunk's LDS reads done
        int si = srow * 72 + skc;
        *(u16x8*)&Ath[si]     = a0;
        *(u16x8*)&Ath[si + 8] = a1;
        *(u16x8*)&Atl[si]     = a2;
        *(u16x8*)&Atl[si + 8] = a3;
        *(u16x8*)&Bth[si]     = b0;
        *(u16x8*)&Bth[si + 8] = b1;
        *(u16x8*)&Btl[si]     = b2;
        *(u16x8*)&Btl[si + 8] = b3;
        __syncthreads();

        #pragma unroll
        for (int ks = 0; ks < 2; ++ks) {
            int bi = (wv * 16 + l15) * 72 + ks * 32 + kg * 8;
            short8 bh = *(const short8*)&Bth[bi];
            short8 bl = *(const short8*)&Btl[bi];
            #pragma unroll
            for (int mt = 0; mt < 4; ++mt) {
                int ai = (mt * 16 + l15) * 72 + ks * 32 + kg * 8;
                short8 ah = *(const short8*)&Ath[ai];
                short8 al = *(const short8*)&Atl[ai];
                acc[mt] = __builtin_amdgcn_mfma_f32_16x16x32_bf16(ah, bh, acc[mt], 0, 0, 0);
                acc[mt] = __builtin_amdgcn_mfma_f32_16x16x32_bf16(ah, bl, acc[mt], 0, 0, 0);
                acc[mt] = __builtin_amdgcn_mfma_f32_16x16x32_bf16(al, bh, acc[mt], 0, 0, 0);
            }
        }
    }

    // epilogue: tanh + bias -> hi/lo planes
    int h = h0b + wv * 16 + l15;
    float b = bias[t * 256 + h];
    #pragma unroll
    for (int mt = 0; mt < 4; ++mt) {
        #pragma unroll
        for (int r = 0; r < 4; ++r) {
            int al = mt * 16 + kg * 4 + r;
            if (al < cnt) {
                float v = fast_tanh(acc[mt][r] + b);
                u16 hh, ll; f2bf_split(v, hh, ll);
                size_t o = (size_t)(p0 + al) * 256 + h;
                outh[o] = hh;
                outl[o] = ll;
            }
        }
    }
}

// ---------------------------------------------------------------------------
// E_atom = h2 . Wo[t] + bo[t]; accumulate into out[b]. One wave per atom.
// ---------------------------------------------------------------------------
__global__ __launch_bounds__(256) void final_kernel(
    const u16* __restrict__ h2h, const u16* __restrict__ h2l,
    const int* __restrict__ perm, const int* __restrict__ types,
    const float* __restrict__ Wo, const float* __restrict__ bo,
    float* __restrict__ out)
{
    int tid = threadIdx.x;
    int wv = tid >> 6;
    int lane = tid & 63;
    int p = blockIdx.x * 4 + wv;
    int atom = perm[p];
    int t = types[atom];
    const u16* hh = h2h + (size_t)p * 256;
    const u16* hl = h2l + (size_t)p * 256;
    float e = 0.f;
    #pragma unroll
    for (int r = 0; r < 4; ++r) {
        int h = r * 64 + lane;
        e += (bf2f(hh[h]) + bf2f(hl[h])) * Wo[t * 256 + h];
    }
    #pragma unroll
    for (int off = 32; off > 0; off >>= 1)
        e += __shfl_xor(e, off, 64);
    if (lane == 0) atomicAdd(&out[atom >> 9], e + bo[t]);
}

// ---------------------------------------------------------------------------
extern "C" void kernel_launch(void* const* d_in, const int* in_sizes, int n_in,
                              void* d_out, int out_size, void* d_ws, size_t ws_size,
                              hipStream_t stream) {
    const float* sym = (const float*)d_in[0];
    const int*   types = (const int*)d_in[1];
    const float* Wf0 = (const float*)d_in[2];
    const float* bf0 = (const float*)d_in[3];
    const float* Wf1 = (const float*)d_in[4];
    const float* bf1 = (const float*)d_in[5];
    const float* Wf2 = (const float*)d_in[6];
    const float* bf2 = (const float*)d_in[7];
    const float* Wt0 = (const float*)d_in[8];
    const float* bt0 = (const float*)d_in[9];
    const float* Wt1 = (const float*)d_in[10];
    const float* bt1 = (const float*)d_in[11];
    const float* Wt2 = (const float*)d_in[12];
    const float* bt2 = (const float*)d_in[13];
    const float* Wo  = (const float*)d_in[14];
    const float* bo  = (const float*)d_in[15];
    float* out = (float*)d_out;

    char* ws = (char*)d_ws;
    const size_t MB = 1024 * 1024;
    int*  meta = (int*)ws;                          // 1 KB
    int*  perm = (int*)(ws + 1024);                 // 16 KB
    u16*  Dh   = (u16*)(ws + 32768);                // 16 MB
    u16*  Dl   = (u16*)(ws + 32768 + 16 * MB);      // 16 MB
    u16*  h0h  = (u16*)(ws + 32768 + 32 * MB);      // 2 MB each
    u16*  h0l  = (u16*)(ws + 32768 + 34 * MB);
    u16*  h1h  = (u16*)(ws + 32768 + 36 * MB);
    u16*  h1l  = (u16*)(ws + 32768 + 38 * MB);
    u16*  h2h  = (u16*)(ws + 32768 + 40 * MB);
    u16*  h2l  = (u16*)(ws + 32768 + 42 * MB);
    u16*  W0h  = (u16*)(ws + 32768 + 44 * MB);      // 4 MB each
    u16*  W0l  = (u16*)(ws + 32768 + 48 * MB);
    u16*  W1h  = (u16*)(ws + 32768 + 52 * MB);      // 512 KB each
    u16*  W1l  = (u16*)(ws + 32768 + 52 * MB + 512 * 1024);
    u16*  W2h  = (u16*)(ws + 32768 + 53 * MB);
    u16*  W2l  = (u16*)(ws + 32768 + 53 * MB + 512 * 1024);
    u16*  F1h  = (u16*)(ws + 32768 + 54 * MB);      // 16 KB each
    u16*  F1l  = (u16*)(ws + 32768 + 54 * MB + 16 * 1024);
    u16*  F2h  = (u16*)(ws + 32768 + 54 * MB + 32 * 1024);    // 64 KB each
    u16*  F2l  = (u16*)(ws + 32768 + 54 * MB + 96 * 1024);

    hipMemsetAsync(d_out, 0, out_size * sizeof(float), stream);
    build_perm_kernel<<<1, 256, 0, stream>>>(types, perm, meta);

    // weight pre-split (hi/lo planes)
    conv_kernel<<<8,    256, 0, stream>>>(Wf1, F1h, F1l, 4 * 64 * 32);
    conv_kernel<<<32,   256, 0, stream>>>(Wf2, F2h, F2l, 4 * 128 * 64);
    conv_kernel<<<2048, 256, 0, stream>>>(Wt0, W0h, W0l, 4 * 256 * 2048);
    conv_kernel<<<256,  256, 0, stream>>>(Wt1, W1h, W1l, 4 * 256 * 256);
    conv_kernel<<<256,  256, 0, stream>>>(Wt2, W2h, W2l, 4 * 256 * 256);

    filter_kernel<<<NATOMS, 256, 0, stream>>>(sym, types, perm,
                                              Wf0, bf0, F1h, F1l, bf1,
                                              F2h, F2l, bf2, Dh, Dl);

    fit_mfma<<<MAXTILES * 4, 256, 0, stream>>>(Dh,  Dl,  W0h, W0l, bt0, h0h, h0l, 2048, meta);
    fit_mfma<<<MAXTILES * 4, 256, 0, stream>>>(h0h, h0l, W1h, W1l, bt1, h1h, h1l, 256,  meta);
    fit_mfma<<<MAXTILES * 4, 256, 0, stream>>>(h1h, h1l, W2h, W2l, bt2, h2h, h2l, 256,  meta);
    final_kernel<<<NATOMS / 4, 256, 0, stream>>>(h2h, h2l, perm, types, Wo, bo, out);
}

// Round 6
// 214.765 us; speedup vs baseline: 7.2196x; 1.0827x over previous
//
#include <hip/hip_runtime.h>
#include <hip/hip_bf16.h>

// Problem constants
#define NATOMS 4096     // B*N = 8*512
#define S_ 128
#define DESC_ 2048
#define H_ 256
#define MAXTILES 67     // sum ceil(cnt_t/64) <= 64+3

typedef short short8 __attribute__((ext_vector_type(8)));
typedef float f32x4 __attribute__((ext_vector_type(4)));
typedef unsigned short u16x8 __attribute__((ext_vector_type(8)));
typedef unsigned short u16x4 __attribute__((ext_vector_type(4)));
typedef unsigned short u16;

__device__ __forceinline__ float fast_tanh(float x) {
    float e = __expf(2.0f * x);
    return 1.0f - 2.0f * __builtin_amdgcn_rcpf(e + 1.0f);
}

__device__ __forceinline__ float bf2f(u16 h) {
    union { unsigned int u; float f; } v; v.u = ((unsigned int)h) << 16;
    return v.f;
}
// truncation split: x ~= hi + lo to ~2^-15 rel, 3 VALU ops
__device__ __forceinline__ void f2bf_split(float x, u16& hi, u16& lo) {
    union { float f; unsigned int u; } v; v.f = x;
    unsigned int hb = v.u & 0xffff0000u;
    hi = (u16)(hb >> 16);
    union { unsigned int u; float f; } w; w.u = hb;
    union { float f; unsigned int u; } z; z.f = x - w.f;
    lo = (u16)(z.u >> 16);
}

// ---------------------------------------------------------------------------
// Counting sort by type + 64-atom type-pure tiles.
// ---------------------------------------------------------------------------
__global__ __launch_bounds__(256) void build_perm_kernel(
    const int* __restrict__ types, int* __restrict__ perm, int* __restrict__ meta)
{
    __shared__ int cnt[256 * 4];
    __shared__ int tot[4];
    __shared__ int tstart[4];
    int tid = threadIdx.x;
    int base = tid * 16;
    int c0 = 0, c1 = 0, c2 = 0, c3 = 0;
    for (int i = 0; i < 16; ++i) {
        int t = types[base + i];
        c0 += (t == 0); c1 += (t == 1); c2 += (t == 2); c3 += (t == 3);
    }
    cnt[tid * 4 + 0] = c0; cnt[tid * 4 + 1] = c1;
    cnt[tid * 4 + 2] = c2; cnt[tid * 4 + 3] = c3;
    __syncthreads();
    if (tid < 4) {   // per-type exclusive scan, one lane per type
        int run = 0;
        for (int th = 0; th < 256; ++th) {
            int v = cnt[th * 4 + tid];
            cnt[th * 4 + tid] = run;
            run += v;
        }
        tot[tid] = run;
    }
    __syncthreads();
    if (tid == 0) {
        int run = 0, nt = 0;
        for (int t = 0; t < 4; ++t) { tstart[t] = run; run += tot[t]; }
        for (int t = 0; t < 4; ++t) {
            int cT = tot[t];
            for (int off = 0; off < cT; off += 64) {
                meta[1 + nt * 3 + 0] = t;
                meta[1 + nt * 3 + 1] = tstart[t] + off;
                meta[1 + nt * 3 + 2] = (cT - off < 64) ? (cT - off) : 64;
                nt++;
            }
        }
        meta[0] = nt;
    }
    __syncthreads();
    for (int i = 0; i < 16; ++i) {
        int idx = base + i;
        int t = types[idx];
        perm[tstart[t] + cnt[tid * 4 + t]++] = idx;
    }
}

// ---------------------------------------------------------------------------
// Split fp32 array into hi/lo bf16 planes.
// ---------------------------------------------------------------------------
__global__ __launch_bounds__(256) void conv_kernel(
    const float* __restrict__ src, u16* __restrict__ dh, u16* __restrict__ dl, int n)
{
    int idx = (blockIdx.x * 256 + threadIdx.x) * 4;
    if (idx >= n) return;
    float4 v = *(const float4*)(src + idx);
    u16x4 oh, ol;
    u16 h, l;
    f2bf_split(v.x, h, l); oh[0] = h; ol[0] = l;
    f2bf_split(v.y, h, l); oh[1] = h; ol[1] = l;
    f2bf_split(v.z, h, l); oh[2] = h; ol[2] = l;
    f2bf_split(v.w, h, l); oh[3] = h; ol[3] = l;
    *(u16x4*)(dh + idx) = oh;
    *(u16x4*)(dl + idx) = ol;
}

// ---------------------------------------------------------------------------
// Filter net + descriptor per atom, split-bf16 MFMA.
// G0 is computed directly in MFMA A-fragment layout in registers (no LDS, no
// extra barrier). LDS = 40960 B exactly -> 4 blocks/CU (16 waves).
//   Rl  [128][4] f32 @0   G1h [128][72] @2048   G1l @20480
//   RGl [4][128] f32 @38912
// ---------------------------------------------------------------------------
__global__ __launch_bounds__(256) void filter_kernel(
    const float* __restrict__ sym, const int* __restrict__ types,
    const int* __restrict__ perm,
    const float* __restrict__ Wf0, const float* __restrict__ bf0,
    const u16* __restrict__ F1h, const u16* __restrict__ F1l,
    const float* __restrict__ bf1,
    const u16* __restrict__ F2h, const u16* __restrict__ F2l,
    const float* __restrict__ bf2,
    u16* __restrict__ Dh, u16* __restrict__ Dl)
{
    __shared__ char lds[40960] __attribute__((aligned(16)));
    float* Rl  = (float*)lds;            // [128][4]
    u16*   G1h = (u16*)(lds + 2048);     // [128][72]
    u16*   G1l = (u16*)(lds + 20480);    // [128][72]
    float* RGl = (float*)(lds + 38912);  // [4][128]

    int p = blockIdx.x;
    int tid = threadIdx.x;
    int atom = perm[p];
    int t = __builtin_amdgcn_readfirstlane(types[atom]);
    int lane = tid & 63;
    int wv   = tid >> 6;
    int kg   = lane >> 4;
    int l15  = lane & 15;

    // ---- Rl staging (used by phase 4 only; barrier below covers it) ------
    ((float2*)Rl)[tid] = ((const float2*)(sym + (size_t)atom * 512))[tid];

    // ---- L0 in registers (A-fragment layout) + L1 MFMA -> G1 hi/lo -------
    {
        // W0/b0 for this thread's k-columns f = kg*8 .. kg*8+7
        const float4* w0p = (const float4*)(Wf0 + t * 32 + kg * 8);
        float4 w04 = w0p[0], w14 = w0p[1];
        const float4* b0p = (const float4*)(bf0 + t * 32 + kg * 8);
        float4 b04 = b0p[0], b14 = b0p[1];

        short8 ah[2], al[2];
        #pragma unroll
        for (int mi = 0; mi < 2; ++mi) {
            int s = (wv * 2 + mi) * 16 + l15;
            float sv = sym[(size_t)atom * 512 + s * 4];   // L1-hit (Rl load above)
            float g[8];
            g[0] = fast_tanh(sv * w04.x + b04.x);
            g[1] = fast_tanh(sv * w04.y + b04.y);
            g[2] = fast_tanh(sv * w04.z + b04.z);
            g[3] = fast_tanh(sv * w04.w + b04.w);
            g[4] = fast_tanh(sv * w14.x + b14.x);
            g[5] = fast_tanh(sv * w14.y + b14.y);
            g[6] = fast_tanh(sv * w14.z + b14.z);
            g[7] = fast_tanh(sv * w14.w + b14.w);
            #pragma unroll
            for (int j = 0; j < 8; ++j) {
                u16 h, l; f2bf_split(g[j], h, l);
                ah[mi][j] = (short)h; al[mi][j] = (short)l;
            }
        }

        short8 b1h[4], b1l[4];
        float  bias1[4];
        #pragma unroll
        for (int nt = 0; nt < 4; ++nt) {
            int off = t * 2048 + (nt * 16 + l15) * 32 + kg * 8;
            b1h[nt] = *(const short8*)(F1h + off);
            b1l[nt] = *(const short8*)(F1l + off);
            bias1[nt] = bf1[t * 64 + nt * 16 + l15];
        }
        #pragma unroll
        for (int mi = 0; mi < 2; ++mi) {
            int mt = wv * 2 + mi;
            #pragma unroll
            for (int nt = 0; nt < 4; ++nt) {
                f32x4 acc = {0.f, 0.f, 0.f, 0.f};
                acc = __builtin_amdgcn_mfma_f32_16x16x32_bf16(ah[mi], b1h[nt], acc, 0, 0, 0);
                acc = __builtin_amdgcn_mfma_f32_16x16x32_bf16(ah[mi], b1l[nt], acc, 0, 0, 0);
                acc = __builtin_amdgcn_mfma_f32_16x16x32_bf16(al[mi], b1h[nt], acc, 0, 0, 0);
                int rowb = mt * 16 + kg * 4;
                #pragma unroll
                for (int r = 0; r < 4; ++r) {
                    u16 h, l;
                    f2bf_split(fast_tanh(acc[r] + bias1[nt]), h, l);
                    G1h[(rowb + r) * 72 + nt * 16 + l15] = h;
                    G1l[(rowb + r) * 72 + nt * 16 + l15] = l;
                }
            }
        }
    }
    __syncthreads();

    // ---- L2 (K=64) fused with RG contraction -----------------------------
    {
        short8 b2h[2][2], b2l[2][2];
        float  bias2[2];
        #pragma unroll
        for (int ntl = 0; ntl < 2; ++ntl) {
            int nt = wv * 2 + ntl;
            bias2[ntl] = bf2[t * 128 + nt * 16 + l15];
            #pragma unroll
            for (int ks = 0; ks < 2; ++ks) {
                int off = t * 8192 + (nt * 16 + l15) * 64 + ks * 32 + kg * 8;
                b2h[ntl][ks] = *(const short8*)(F2h + off);
                b2l[ntl][ks] = *(const short8*)(F2l + off);
            }
        }
        float rg[4][2];
        #pragma unroll
        for (int d = 0; d < 4; ++d) { rg[d][0] = 0.f; rg[d][1] = 0.f; }

        #pragma unroll 2
        for (int mt = 0; mt < 8; ++mt) {
            int i0 = (mt * 16 + l15) * 72 + kg * 8;
            short8 a0h = *(const short8*)&G1h[i0];
            short8 a0l = *(const short8*)&G1l[i0];
            short8 a1h = *(const short8*)&G1h[i0 + 32];
            short8 a1l = *(const short8*)&G1l[i0 + 32];
            f32x4 acc0 = {0.f,0.f,0.f,0.f}, acc1 = {0.f,0.f,0.f,0.f};
            acc0 = __builtin_amdgcn_mfma_f32_16x16x32_bf16(a0h, b2h[0][0], acc0, 0,0,0);
            acc0 = __builtin_amdgcn_mfma_f32_16x16x32_bf16(a0h, b2l[0][0], acc0, 0,0,0);
            acc0 = __builtin_amdgcn_mfma_f32_16x16x32_bf16(a0l, b2h[0][0], acc0, 0,0,0);
            acc0 = __builtin_amdgcn_mfma_f32_16x16x32_bf16(a1h, b2h[0][1], acc0, 0,0,0);
            acc0 = __builtin_amdgcn_mfma_f32_16x16x32_bf16(a1h, b2l[0][1], acc0, 0,0,0);
            acc0 = __builtin_amdgcn_mfma_f32_16x16x32_bf16(a1l, b2h[0][1], acc0, 0,0,0);
            acc1 = __builtin_amdgcn_mfma_f32_16x16x32_bf16(a0h, b2h[1][0], acc1, 0,0,0);
            acc1 = __builtin_amdgcn_mfma_f32_16x16x32_bf16(a0h, b2l[1][0], acc1, 0,0,0);
            acc1 = __builtin_amdgcn_mfma_f32_16x16x32_bf16(a0l, b2h[1][0], acc1, 0,0,0);
            acc1 = __builtin_amdgcn_mfma_f32_16x16x32_bf16(a1h, b2h[1][1], acc1, 0,0,0);
            acc1 = __builtin_amdgcn_mfma_f32_16x16x32_bf16(a1h, b2l[1][1], acc1, 0,0,0);
            acc1 = __builtin_amdgcn_mfma_f32_16x16x32_bf16(a1l, b2h[1][1], acc1, 0,0,0);
            int rowb = mt * 16 + kg * 4;
            #pragma unroll
            for (int r = 0; r < 4; ++r) {
                float4 R4 = *(const float4*)&Rl[(rowb + r) * 4];
                float g0 = fast_tanh(acc0[r] + bias2[0]);
                float g1 = fast_tanh(acc1[r] + bias2[1]);
                rg[0][0] += R4.x * g0; rg[1][0] += R4.y * g0;
                rg[2][0] += R4.z * g0; rg[3][0] += R4.w * g0;
                rg[0][1] += R4.x * g1; rg[1][1] += R4.y * g1;
                rg[2][1] += R4.z * g1; rg[3][1] += R4.w * g1;
            }
        }
        #pragma unroll
        for (int off = 16; off < 64; off <<= 1) {
            #pragma unroll
            for (int d = 0; d < 4; ++d) {
                rg[d][0] += __shfl_xor(rg[d][0], off, 64);
                rg[d][1] += __shfl_xor(rg[d][1], off, 64);
            }
        }
        if (kg == 0) {
            #pragma unroll
            for (int d = 0; d < 4; ++d) {
                RGl[d * 128 + wv * 32 + l15]      = rg[d][0];
                RGl[d * 128 + wv * 32 + 16 + l15] = rg[d][1];
            }
        }
    }
    __syncthreads();

    // ---- GRRG -> D hi/lo planes ------------------------------------------
    {
        int m = tid >> 1;
        int ab = (tid & 1) * 8;
        float rm0 = RGl[0 * 128 + m], rm1 = RGl[1 * 128 + m];
        float rm2 = RGl[2 * 128 + m], rm3 = RGl[3 * 128 + m];
        u16x8 oh, ol;
        #pragma unroll
        for (int q = 0; q < 8; ++q) {
            int a = ab + q;
            float v = rm0 * RGl[0 * 128 + a] + rm1 * RGl[1 * 128 + a]
                    + rm2 * RGl[2 * 128 + a] + rm3 * RGl[3 * 128 + a];
            u16 h, l; f2bf_split(v, h, l);
            oh[q] = h; ol[q] = l;
        }
        size_t base = (size_t)p * DESC_ + m * 16 + ab;
        *(u16x8*)(Dh + base) = oh;
        *(u16x8*)(Dl + base) = ol;
    }
}

// ---------------------------------------------------------------------------
// MFMA fitting layer. Block = 64 atoms x 64 h. grid = MAXTILES*4 (all CUs).
// 4 waves; wave = 64a x 16h = 4 m-tiles. KC=64 chunks, LDS 36 KB -> 4 blk/CU.
// ---------------------------------------------------------------------------
__global__ __launch_bounds__(256) void fit_mfma(
    const u16* __restrict__ inh, const u16* __restrict__ inl,
    const u16* __restrict__ Wh,  const u16* __restrict__ Wl,
    const float* __restrict__ bias,
    u16* __restrict__ outh, u16* __restrict__ outl,
    int K, const int* __restrict__ meta)
{
    __shared__ char lds[36864] __attribute__((aligned(16)));
    u16* Ath = (u16*)lds;             // [64][72]
    u16* Atl = (u16*)(lds + 9216);
    u16* Bth = (u16*)(lds + 18432);   // [64][72]
    u16* Btl = (u16*)(lds + 27648);

    int ntiles = meta[0];
    int tile = blockIdx.x >> 2;
    if (tile >= ntiles) return;
    int hq  = blockIdx.x & 3;
    int t   = __builtin_amdgcn_readfirstlane(meta[1 + tile * 3 + 0]);
    int p0  = meta[1 + tile * 3 + 1];
    int cnt = meta[1 + tile * 3 + 2];
    int h0b = hq * 64;

    int tid = threadIdx.x;
    int lane = tid & 63;
    int wv   = tid >> 6;
    int kg   = lane >> 4;
    int l15  = lane & 15;

    int srow = tid >> 2;          // 0..63
    int skc  = (tid & 3) * 16;    // k offset within chunk
    int agrow = p0 + srow; if (agrow > NATOMS - 1) agrow = NATOMS - 1;
    const u16* arow_h = inh + (size_t)agrow * K;
    const u16* arow_l = inl + (size_t)agrow * K;
    const u16* brow_h = Wh + ((size_t)t * 256 + h0b + srow) * K;
    const u16* brow_l = Wl + ((size_t)t * 256 + h0b + srow) * K;

    f32x4 acc[4];
    #pragma unroll
    for (int mt = 0; mt < 4; ++mt) acc[mt] = (f32x4){0.f, 0.f, 0.f, 0.f};

    for (int k0 = 0; k0 < K; k0 += 64) {
        u16x8 a0 = *(const u16x8*)(arow_h + k0 + skc);
        u16x8 a1 = *(const u16x8*)(arow_h + k0 + skc + 8);
        u16x8 a2 = *(const u16x8*)(arow_l + k0 + skc);
        u16x8 a3 = *(const u16x8*)(arow_l + k0 + skc + 8);
        u16x8 b0 = *(const u16x8*)(brow_h + k0 + skc);
        u16x8 b1 = *(const u16x8*)(brow_h + k0 + skc + 8);
        u16x8 b2 = *(const u16x8*)(brow_l + k0 + skc);
        u16x8 b3 = *(const u16x8*)(brow_l + k0 + skc + 8);
        __syncthreads();   // previous chunk's LDS reads done
        int si = srow * 72 + skc;
        *(u16x8*)&Ath[si]     = a0;
        *(u16x8*)&Ath[si + 8] = a1;
        *(u16x8*)&Atl[si]     = a2;
        *(u16x8*)&Atl[si + 8] = a3;
        *(u16x8*)&Bth[si]     = b0;
        *(u16x8*)&Bth[si + 8] = b1;
        *(u16x8*)&Btl[si]     = b2;
        *(u16x8*)&Btl[si + 8] = b3;
        __syncthreads();

        #pragma unroll
        for (int ks = 0; ks < 2; ++ks) {
            int bi = (wv * 16 + l15) * 72 + ks * 32 + kg * 8;
            short8 bh = *(const short8*)&Bth[bi];
            short8 bl = *(const short8*)&Btl[bi];
            #pragma unroll
            for (int mt = 0; mt < 4; ++mt) {
                int ai = (mt * 16 + l15) * 72 + ks * 32 + kg * 8;
                short8 ah = *(const short8*)&Ath[ai];
                short8 al = *(const short8*)&Atl[ai];
                acc[mt] = __builtin_amdgcn_mfma_f32_16x16x32_bf16(ah, bh, acc[mt], 0, 0, 0);
                acc[mt] = __builtin_amdgcn_mfma_f32_16x16x32_bf16(ah, bl, acc[mt], 0, 0, 0);
                acc[mt] = __builtin_amdgcn_mfma_f32_16x16x32_bf16(al, bh, acc[mt], 0, 0, 0);
            }
        }
    }

    // epilogue: tanh + bias -> hi/lo planes
    int h = h0b + wv * 16 + l15;
    float b = bias[t * 256 + h];
    #pragma unroll
    for (int mt = 0; mt < 4; ++mt) {
        #pragma unroll
        for (int r = 0; r < 4; ++r) {
            int al = mt * 16 + kg * 4 + r;
            if (al < cnt) {
                float v = fast_tanh(acc[mt][r] + b);
                u16 hh, ll; f2bf_split(v, hh, ll);
                size_t o = (size_t)(p0 + al) * 256 + h;
                outh[o] = hh;
                outl[o] = ll;
            }
        }
    }
}

// ---------------------------------------------------------------------------
// E_atom = h2 . Wo[t] + bo[t]; accumulate into out[b]. One wave per atom.
// ---------------------------------------------------------------------------
__global__ __launch_bounds__(256) void final_kernel(
    const u16* __restrict__ h2h, const u16* __restrict__ h2l,
    const int* __restrict__ perm, const int* __restrict__ types,
    const float* __restrict__ Wo, const float* __restrict__ bo,
    float* __restrict__ out)
{
    int tid = threadIdx.x;
    int wv = tid >> 6;
    int lane = tid & 63;
    int p = blockIdx.x * 4 + wv;
    int atom = perm[p];
    int t = types[atom];
    const u16* hh = h2h + (size_t)p * 256;
    const u16* hl = h2l + (size_t)p * 256;
    float e = 0.f;
    #pragma unroll
    for (int r = 0; r < 4; ++r) {
        int h = r * 64 + lane;
        e += (bf2f(hh[h]) + bf2f(hl[h])) * Wo[t * 256 + h];
    }
    #pragma unroll
    for (int off = 32; off > 0; off >>= 1)
        e += __shfl_xor(e, off, 64);
    if (lane == 0) atomicAdd(&out[atom >> 9], e + bo[t]);
}

// ---------------------------------------------------------------------------
extern "C" void kernel_launch(void* const* d_in, const int* in_sizes, int n_in,
                              void* d_out, int out_size, void* d_ws, size_t ws_size,
                              hipStream_t stream) {
    const float* sym = (const float*)d_in[0];
    const int*   types = (const int*)d_in[1];
    const float* Wf0 = (const float*)d_in[2];
    const float* bf0 = (const float*)d_in[3];
    const float* Wf1 = (const float*)d_in[4];
    const float* bf1 = (const float*)d_in[5];
    const float* Wf2 = (const float*)d_in[6];
    const float* bf2 = (const float*)d_in[7];
    const float* Wt0 = (const float*)d_in[8];
    const float* bt0 = (const float*)d_in[9];
    const float* Wt1 = (const float*)d_in[10];
    const float* bt1 = (const float*)d_in[11];
    const float* Wt2 = (const float*)d_in[12];
    const float* bt2 = (const float*)d_in[13];
    const float* Wo  = (const float*)d_in[14];
    const float* bo  = (const float*)d_in[15];
    float* out = (float*)d_out;

    char* ws = (char*)d_ws;
    const size_t MB = 1024 * 1024;
    int*  meta = (int*)ws;                          // 1 KB
    int*  perm = (int*)(ws + 1024);                 // 16 KB
    u16*  Dh   = (u16*)(ws + 32768);                // 16 MB
    u16*  Dl   = (u16*)(ws + 32768 + 16 * MB);      // 16 MB
    u16*  h0h  = (u16*)(ws + 32768 + 32 * MB);      // 2 MB each
    u16*  h0l  = (u16*)(ws + 32768 + 34 * MB);
    u16*  h1h  = (u16*)(ws + 32768 + 36 * MB);
    u16*  h1l  = (u16*)(ws + 32768 + 38 * MB);
    u16*  h2h  = (u16*)(ws + 32768 + 40 * MB);
    u16*  h2l  = (u16*)(ws + 32768 + 42 * MB);
    u16*  W0h  = (u16*)(ws + 32768 + 44 * MB);      // 4 MB each
    u16*  W0l  = (u16*)(ws + 32768 + 48 * MB);
    u16*  W1h  = (u16*)(ws + 32768 + 52 * MB);      // 512 KB each
    u16*  W1l  = (u16*)(ws + 32768 + 52 * MB + 512 * 1024);
    u16*  W2h  = (u16*)(ws + 32768 + 53 * MB);
    u16*  W2l  = (u16*)(ws + 32768 + 53 * MB + 512 * 1024);
    u16*  F1h  = (u16*)(ws + 32768 + 54 * MB);      // 16 KB each
    u16*  F1l  = (u16*)(ws + 32768 + 54 * MB + 16 * 1024);
    u16*  F2h  = (u16*)(ws + 32768 + 54 * MB + 32 * 1024);    // 64 KB each
    u16*  F2l  = (u16*)(ws + 32768 + 54 * MB + 96 * 1024);

    hipMemsetAsync(d_out, 0, out_size * sizeof(float), stream);
    build_perm_kernel<<<1, 256, 0, stream>>>(types, perm, meta);

    // weight pre-split (hi/lo planes)
    conv_kernel<<<8,    256, 0, stream>>>(Wf1, F1h, F1l, 4 * 64 * 32);
    conv_kernel<<<32,   256, 0, stream>>>(Wf2, F2h, F2l, 4 * 128 * 64);
    conv_kernel<<<2048, 256, 0, stream>>>(Wt0, W0h, W0l, 4 * 256 * 2048);
    conv_kernel<<<256,  256, 0, stream>>>(Wt1, W1h, W1l, 4 * 256 * 256);
    conv_kernel<<<256,  256, 0, stream>>>(Wt2, W2h, W2l, 4 * 256 * 256);

    filter_kernel<<<NATOMS, 256, 0, stream>>>(sym, types, perm,
                                              Wf0, bf0, F1h, F1l, bf1,
                                              F2h, F2l, bf2, Dh, Dl);

    fit_mfma<<<MAXTILES * 4, 256, 0, stream>>>(Dh,  Dl,  W0h, W0l, bt0, h0h, h0l, 2048, meta);
    fit_mfma<<<MAXTILES * 4, 256, 0, stream>>>(h0h, h0l, W1h, W1l, bt1, h1h, h1l, 256,  meta);
    fit_mfma<<<MAXTILES * 4, 256, 0, stream>>>(h1h, h1l, W2h, W2l, bt2, h2h, h2l, 256,  meta);
    final_kernel<<<NATOMS / 4, 256, 0, stream>>>(h2h, h2l, perm, types, Wo, bo, out);
}